// Round 2
// baseline (969.049 us; speedup 1.0000x reference)
//
#include <hip/hip_runtime.h>

#define S_LEN 2048
#define NH 16
#define DKH 128
#define LDIM 64

typedef unsigned short u16;
typedef __attribute__((ext_vector_type(8))) short bf16x8;
typedef __attribute__((ext_vector_type(4))) short s16x4;
typedef __attribute__((ext_vector_type(4))) unsigned short u16x4;
typedef __attribute__((ext_vector_type(4))) float f32x4;

__device__ __forceinline__ float bf2f(u16 u) {
  union { unsigned int i; float f; } x; x.i = ((unsigned int)u) << 16; return x.f;
}
__device__ __forceinline__ u16 f2bf(float f) {
  union { float f; unsigned int i; } x; x.f = f;
  unsigned int r = x.i + 0x7FFFu + ((x.i >> 16) & 1u);
  return (u16)(r >> 16);
}
__device__ __forceinline__ void glds16(const void* g, void* l) {
  __builtin_amdgcn_global_load_lds((const __attribute__((address_space(1))) void*)g,
                                   (__attribute__((address_space(3))) void*)l, 16, 0, 0);
}

// ---------------- transpose+cast: in [K,N] fp32 -> out [N,K] bf16 ----------------
__global__ __launch_bounds__(256) void transpose_f32_bf16(const float* __restrict__ in,
                                                          u16* __restrict__ out,
                                                          int K, int N) {
  __shared__ u16 tile[64][72];
  int k0 = blockIdx.y * 64, n0 = blockIdx.x * 64;
  int t = threadIdx.x;
#pragma unroll
  for (int i = 0; i < 4; ++i) {
    int idx = i * 256 + t;
    int r = idx >> 4;
    int c4 = (idx & 15) << 2;
    f32x4 v = *(const f32x4*)&in[(size_t)(k0 + r) * N + n0 + c4];
#pragma unroll
    for (int j = 0; j < 4; ++j) tile[r][c4 + j] = f2bf(v[j]);
  }
  __syncthreads();
#pragma unroll
  for (int i = 0; i < 4; ++i) {
    int idx = i * 256 + t;
    int r = idx >> 4;
    int c4 = (idx & 15) << 2;
    u16x4 v;
    v[0] = tile[c4 + 0][r];
    v[1] = tile[c4 + 1][r];
    v[2] = tile[c4 + 2][r];
    v[3] = tile[c4 + 3][r];
    *(u16x4*)&out[(size_t)(n0 + r) * K + k0 + c4] = v;
  }
}

// ------------- GEMM: C[M,N] = A[M,K] @ W[K,N] + bias, W transposed bf16 Wt[N,K] -------------
// AF32: A is fp32 (reg-staged+cast); else bf16 (global_load_lds).  OF32: C fp32; else bf16.
template <bool AF32, bool OF32>
__global__ __launch_bounds__(256) void gemm_bt_bias(const void* __restrict__ Av,
                                                    const u16* __restrict__ Wt,
                                                    const float* __restrict__ bias,
                                                    void* __restrict__ Cv,
                                                    int M, int N, int K) {
  __shared__ u16 lA[128 * 64];
  __shared__ u16 lB[128 * 64];
  int m0 = blockIdx.y * 128, n0 = blockIdx.x * 128;
  int t = threadIdx.x;
  int lane = t & 63, lq = lane & 15, hi = lane >> 4;
  int w = t >> 6, wm = w >> 1, wn = w & 1;

  f32x4 acc[4][4];
#pragma unroll
  for (int im = 0; im < 4; ++im)
#pragma unroll
    for (int in = 0; in < 4; ++in) acc[im][in] = (f32x4){0.f, 0.f, 0.f, 0.f};

  for (int k0 = 0; k0 < K; k0 += 64) {
    __syncthreads();
    // B tile: bf16, async global->LDS, width 16
#pragma unroll
    for (int i = 0; i < 4; ++i) {
      int idx = i * 256 + t;
      int r = idx >> 3, c8 = (idx & 7) << 3;
      glds16(&Wt[(size_t)(n0 + r) * K + k0 + c8], &lB[idx * 8]);
    }
    // A tile
    if constexpr (AF32) {
      const float* A = (const float*)Av;
#pragma unroll
      for (int i = 0; i < 8; ++i) {
        int idx = i * 256 + t;
        int r = idx >> 4, c4 = (idx & 15) << 2;
        f32x4 av = *(const f32x4*)&A[(size_t)(m0 + r) * K + k0 + c4];
        s16x4 bv;
#pragma unroll
        for (int j = 0; j < 4; ++j) bv[j] = (short)f2bf(av[j]);
        *(s16x4*)&lA[r * 64 + c4] = bv;
      }
    } else {
      const u16* A = (const u16*)Av;
#pragma unroll
      for (int i = 0; i < 4; ++i) {
        int idx = i * 256 + t;
        int r = idx >> 3, c8 = (idx & 7) << 3;
        glds16(&A[(size_t)(m0 + r) * K + k0 + c8], &lA[idx * 8]);
      }
    }
    __syncthreads();
#pragma unroll
    for (int kk = 0; kk < 2; ++kk) {
      bf16x8 af[4], bfr[4];
#pragma unroll
      for (int im = 0; im < 4; ++im)
        af[im] = *(const bf16x8*)&lA[(wm * 64 + im * 16 + lq) * 64 + kk * 32 + hi * 8];
#pragma unroll
      for (int in = 0; in < 4; ++in)
        bfr[in] = *(const bf16x8*)&lB[(wn * 64 + in * 16 + lq) * 64 + kk * 32 + hi * 8];
#pragma unroll
      for (int im = 0; im < 4; ++im)
#pragma unroll
        for (int in = 0; in < 4; ++in)
          acc[im][in] = __builtin_amdgcn_mfma_f32_16x16x32_bf16(af[im], bfr[in], acc[im][in], 0, 0, 0);
    }
  }
#pragma unroll
  for (int im = 0; im < 4; ++im)
#pragma unroll
    for (int in = 0; in < 4; ++in) {
      int col = n0 + wn * 64 + in * 16 + lq;
      float bv = bias[col];
      int rbase = m0 + wm * 64 + im * 16 + hi * 4;
#pragma unroll
      for (int r = 0; r < 4; ++r) {
        float v = acc[im][in][r] + bv;
        if constexpr (OF32)
          ((float*)Cv)[(size_t)(rbase + r) * N + col] = v;
        else
          ((u16*)Cv)[(size_t)(rbase + r) * N + col] = f2bf(v);
      }
    }
}

// ------------- recon K: Kf[bh][s][dk] = LK[b,s,h*64+ld] @ Wkr[ld,dk] (WkrT [dk][ld] bf16) -------------
__global__ __launch_bounds__(256) void recon_k(const u16* __restrict__ L,
                                               const u16* __restrict__ WT,
                                               u16* __restrict__ out) {
  int bh = blockIdx.y, st = blockIdx.x;
  int b = bh >> 4, h = bh & 15;
  int t = threadIdx.x, w = t >> 6, lane = t & 63, lq = lane & 15, hi = lane >> 4;
  int s0 = st * 64 + w * 16;
  const u16* lrow = L + (size_t)(b * S_LEN + s0 + lq) * (NH * LDIM) + h * LDIM;
  bf16x8 a0 = *(const bf16x8*)&lrow[hi * 8];
  bf16x8 a1 = *(const bf16x8*)&lrow[32 + hi * 8];
  u16* obase = out + (size_t)bh * S_LEN * DKH;
#pragma unroll
  for (int fn = 0; fn < 8; ++fn) {
    const u16* wrow = WT + (size_t)(fn * 16 + lq) * LDIM;
    bf16x8 b0 = *(const bf16x8*)&wrow[hi * 8];
    bf16x8 b1 = *(const bf16x8*)&wrow[32 + hi * 8];
    f32x4 acc = (f32x4){0.f, 0.f, 0.f, 0.f};
    acc = __builtin_amdgcn_mfma_f32_16x16x32_bf16(a0, b0, acc, 0, 0, 0);
    acc = __builtin_amdgcn_mfma_f32_16x16x32_bf16(a1, b1, acc, 0, 0, 0);
#pragma unroll
    for (int r = 0; r < 4; ++r)
      obase[(size_t)(s0 + hi * 4 + r) * DKH + fn * 16 + lq] = f2bf(acc[r]);
  }
}

// ------------- recon V^T: Vt[bh][dv][s] (WvrT [dv][ld] bf16) -------------
__global__ __launch_bounds__(256) void recon_vt(const u16* __restrict__ L,
                                                const u16* __restrict__ WT,
                                                u16* __restrict__ out) {
  int bh = blockIdx.y, st = blockIdx.x;
  int b = bh >> 4, h = bh & 15;
  int t = threadIdx.x, w = t >> 6, lane = t & 63, lq = lane & 15, hi = lane >> 4;
  u16* obase = out + (size_t)bh * DKH * S_LEN;
  bf16x8 bfr[4][2];
#pragma unroll
  for (int fs = 0; fs < 4; ++fs) {
    const u16* lrow = L + (size_t)(b * S_LEN + st * 64 + fs * 16 + lq) * (NH * LDIM) + h * LDIM;
    bfr[fs][0] = *(const bf16x8*)&lrow[hi * 8];
    bfr[fs][1] = *(const bf16x8*)&lrow[32 + hi * 8];
  }
#pragma unroll
  for (int fd = 0; fd < 2; ++fd) {
    int dv0 = w * 32 + fd * 16;
    const u16* wrow = WT + (size_t)(dv0 + lq) * LDIM;
    bf16x8 a0 = *(const bf16x8*)&wrow[hi * 8];
    bf16x8 a1 = *(const bf16x8*)&wrow[32 + hi * 8];
#pragma unroll
    for (int fs = 0; fs < 4; ++fs) {
      f32x4 acc = (f32x4){0.f, 0.f, 0.f, 0.f};
      acc = __builtin_amdgcn_mfma_f32_16x16x32_bf16(a0, bfr[fs][0], acc, 0, 0, 0);
      acc = __builtin_amdgcn_mfma_f32_16x16x32_bf16(a1, bfr[fs][1], acc, 0, 0, 0);
#pragma unroll
      for (int r = 0; r < 4; ++r)
        obase[(size_t)(dv0 + hi * 4 + r) * S_LEN + st * 64 + fs * 16 + lq] = f2bf(acc[r]);
    }
  }
}

// ------------- flash attention (causal), swapped QK^T, O^T accumulation -------------
__global__ __launch_bounds__(256) void mla_attn(const u16* __restrict__ Qp,
                                                const u16* __restrict__ Kf,
                                                const u16* __restrict__ Vt,
                                                u16* __restrict__ O) {
  __shared__ u16 lo[4 * 16 * 128];
  int bh = blockIdx.y;
  int b = bh >> 4, h = bh & 15;
  int qt = blockIdx.x;
  int t = threadIdx.x, w = t >> 6, lane = t & 63, lq = lane & 15, hi = lane >> 4;
  int q0 = qt * 64 + w * 16;

  const u16* Qrow = Qp + (size_t)(b * S_LEN + q0 + lq) * 2048 + h * 128;
  bf16x8 qf[4];
#pragma unroll
  for (int d0 = 0; d0 < 4; ++d0) qf[d0] = *(const bf16x8*)&Qrow[d0 * 32 + hi * 8];

  const u16* Kb = Kf + (size_t)bh * S_LEN * DKH;
  const u16* Vb = Vt + (size_t)bh * DKH * S_LEN;

  f32x4 acc[8];
#pragma unroll
  for (int f = 0; f < 8; ++f) acc[f] = (f32x4){0.f, 0.f, 0.f, 0.f};
  float m = -1e30f, l = 0.f;
  const float scale = 0.08838834764831845f;  // 1/sqrt(128)

  int ktiles = (q0 + 16 + 31) >> 5;
  for (int kt = 0; kt < ktiles; ++kt) {
    int k0 = kt * 32;
    f32x4 s0 = (f32x4){0.f, 0.f, 0.f, 0.f};
    f32x4 s1 = (f32x4){0.f, 0.f, 0.f, 0.f};
    const u16* Kr0 = Kb + (size_t)(k0 + lq) * 128;
    const u16* Kr1 = Kb + (size_t)(k0 + 16 + lq) * 128;
#pragma unroll
    for (int d0 = 0; d0 < 4; ++d0) {
      bf16x8 a0 = *(const bf16x8*)&Kr0[d0 * 32 + hi * 8];
      bf16x8 a1 = *(const bf16x8*)&Kr1[d0 * 32 + hi * 8];
      s0 = __builtin_amdgcn_mfma_f32_16x16x32_bf16(a0, qf[d0], s0, 0, 0, 0);
      s1 = __builtin_amdgcn_mfma_f32_16x16x32_bf16(a1, qf[d0], s1, 0, 0, 0);
    }
    float sv[8];
#pragma unroll
    for (int r = 0; r < 4; ++r) { sv[r] = s0[r] * scale; sv[4 + r] = s1[r] * scale; }
    if (k0 + 31 > q0) {  // boundary tile: causal mask
      int q = q0 + lq;
#pragma unroll
      for (int r = 0; r < 4; ++r) {
        if (k0 + hi * 4 + r > q) sv[r] = -1e30f;
        if (k0 + 16 + hi * 4 + r > q) sv[4 + r] = -1e30f;
      }
    }
    float tm = sv[0];
#pragma unroll
    for (int r = 1; r < 8; ++r) tm = fmaxf(tm, sv[r]);
    tm = fmaxf(tm, __shfl_xor(tm, 16));
    tm = fmaxf(tm, __shfl_xor(tm, 32));
    float mnew = fmaxf(m, tm);
    float alpha = __expf(m - mnew);
    float p[8];
    float ps = 0.f;
#pragma unroll
    for (int r = 0; r < 8; ++r) { p[r] = __expf(sv[r] - mnew); ps += p[r]; }
    ps += __shfl_xor(ps, 16);
    ps += __shfl_xor(ps, 32);
    l = l * alpha + ps;
    m = mnew;
#pragma unroll
    for (int f = 0; f < 8; ++f) {
      acc[f][0] *= alpha; acc[f][1] *= alpha; acc[f][2] *= alpha; acc[f][3] *= alpha;
    }
    bf16x8 pb;
#pragma unroll
    for (int r = 0; r < 4; ++r) {
      pb[r] = (short)f2bf(p[r]);
      pb[4 + r] = (short)f2bf(p[4 + r]);
    }
    // PV: A = Vt rows (dv), k-slots k0 + hi*4 + {0..3} and k0 + 16 + hi*4 + {0..3}
#pragma unroll
    for (int f = 0; f < 8; ++f) {
      const u16* vrow = Vb + (size_t)(f * 16 + lq) * S_LEN + k0;
      bf16x8 va;
      *(s16x4*)&va = *(const s16x4*)&vrow[hi * 4];
      *((s16x4*)&va + 1) = *(const s16x4*)&vrow[16 + hi * 4];
      acc[f] = __builtin_amdgcn_mfma_f32_16x16x32_bf16(va, pb, acc[f], 0, 0, 0);
    }
  }
  // epilogue: O^T -> LDS -> coalesced O[q][dv] stores
  float inv = 1.f / l;
  u16* lw = &lo[w * 2048];
#pragma unroll
  for (int f = 0; f < 8; ++f)
#pragma unroll
    for (int r = 0; r < 4; ++r)
      lw[lq * 128 + f * 16 + hi * 4 + r] = f2bf(acc[f][r] * inv);
  __syncthreads();
#pragma unroll
  for (int i = 0; i < 4; ++i) {
    int cid = i * 64 + lane;
    int q = cid >> 4, c8 = (cid & 15) << 3;
    bf16x8 v = *(const bf16x8*)&lw[q * 128 + c8];
    *(bf16x8*)&O[(size_t)(b * S_LEN + q0 + q) * 2048 + h * 128 + c8] = v;
  }
}

extern "C" void kernel_launch(void* const* d_in, const int* in_sizes, int n_in,
                              void* d_out, int out_size, void* d_ws, size_t ws_size,
                              hipStream_t stream) {
  const float* queries = (const float*)d_in[0];
  const float* keys    = (const float*)d_in[1];
  const float* values  = (const float*)d_in[2];
  const float* Wq      = (const float*)d_in[3];
  const float* bq      = (const float*)d_in[4];
  const float* Wlk     = (const float*)d_in[5];
  const float* blk     = (const float*)d_in[6];
  const float* Wlv     = (const float*)d_in[7];
  const float* blv     = (const float*)d_in[8];
  const float* Wkr     = (const float*)d_in[9];
  const float* Wvr     = (const float*)d_in[10];
  const float* Wout    = (const float*)d_in[11];
  const float* bout    = (const float*)d_in[12];

  u16* ws = (u16*)d_ws;
  u16* WqT   = ws; ws += (size_t)2048 * 2048;
  u16* WlkT  = ws; ws += (size_t)1024 * 2048;
  u16* WlvT  = ws; ws += (size_t)1024 * 2048;
  u16* WoutT = ws; ws += (size_t)2048 * 2048;
  u16* WkrT  = ws; ws += 128 * 64;
  u16* WvrT  = ws; ws += 128 * 64;
  u16* Qp    = ws; ws += (size_t)4096 * 2048;
  u16* LKb   = ws; ws += (size_t)4096 * 1024;
  u16* LVb   = ws; ws += (size_t)4096 * 1024;
  u16* Kf    = ws; ws += (size_t)4096 * 2048;
  u16* Vt    = ws; ws += (size_t)4096 * 2048;
  u16* Ob    = ws; ws += (size_t)4096 * 2048;

  dim3 blk256(256);
  transpose_f32_bf16<<<dim3(32, 32), blk256, 0, stream>>>(Wq, WqT, 2048, 2048);
  transpose_f32_bf16<<<dim3(16, 32), blk256, 0, stream>>>(Wlk, WlkT, 2048, 1024);
  transpose_f32_bf16<<<dim3(16, 32), blk256, 0, stream>>>(Wlv, WlvT, 2048, 1024);
  transpose_f32_bf16<<<dim3(32, 32), blk256, 0, stream>>>(Wout, WoutT, 2048, 2048);
  transpose_f32_bf16<<<dim3(2, 1), blk256, 0, stream>>>(Wkr, WkrT, 64, 128);
  transpose_f32_bf16<<<dim3(2, 1), blk256, 0, stream>>>(Wvr, WvrT, 64, 128);

  gemm_bt_bias<true, false><<<dim3(16, 32), blk256, 0, stream>>>(queries, WqT, bq, Qp, 4096, 2048, 2048);
  gemm_bt_bias<true, false><<<dim3(8, 32), blk256, 0, stream>>>(keys, WlkT, blk, LKb, 4096, 1024, 2048);
  gemm_bt_bias<true, false><<<dim3(8, 32), blk256, 0, stream>>>(values, WlvT, blv, LVb, 4096, 1024, 2048);

  recon_k<<<dim3(32, 32), blk256, 0, stream>>>(LKb, WkrT, Kf);
  recon_vt<<<dim3(32, 32), blk256, 0, stream>>>(LVb, WvrT, Vt);

  mla_attn<<<dim3(32, 32), blk256, 0, stream>>>(Qp, Kf, Vt, Ob);

  gemm_bt_bias<false, true><<<dim3(16, 32), blk256, 0, stream>>>(Ob, WoutT, bout, (float*)d_out, 4096, 2048, 2048);
}

// Round 3
// 398.269 us; speedup vs baseline: 2.4331x; 2.4331x over previous
//
#include <hip/hip_runtime.h>

#define S_LEN 2048
#define NH 16
#define DKH 128
#define LDIM 64

typedef unsigned short u16;
typedef __attribute__((ext_vector_type(8))) short bf16x8;
typedef __attribute__((ext_vector_type(4))) short s16x4;
typedef __attribute__((ext_vector_type(4))) unsigned short u16x4;
typedef __attribute__((ext_vector_type(4))) float f32x4;

__device__ __forceinline__ float bf2f(u16 u) {
  union { unsigned int i; float f; } x; x.i = ((unsigned int)u) << 16; return x.f;
}
__device__ __forceinline__ u16 f2bf(float f) {
  union { float f; unsigned int i; } x; x.f = f;
  unsigned int r = x.i + 0x7FFFu + ((x.i >> 16) & 1u);
  return (u16)(r >> 16);
}
__device__ __forceinline__ void glds16(const void* g, void* l) {
  __builtin_amdgcn_global_load_lds((const __attribute__((address_space(1))) void*)g,
                                   (__attribute__((address_space(3))) void*)l, 16, 0, 0);
}

// ---------------- transpose+cast: in [K,N] fp32 -> out [N,K] bf16 ----------------
__global__ __launch_bounds__(256) void transpose_f32_bf16(const float* __restrict__ in,
                                                          u16* __restrict__ out,
                                                          int K, int N) {
  __shared__ u16 tile[64][72];
  int k0 = blockIdx.y * 64, n0 = blockIdx.x * 64;
  int t = threadIdx.x;
#pragma unroll
  for (int i = 0; i < 4; ++i) {
    int idx = i * 256 + t;
    int r = idx >> 4;
    int c4 = (idx & 15) << 2;
    f32x4 v = *(const f32x4*)&in[(size_t)(k0 + r) * N + n0 + c4];
#pragma unroll
    for (int j = 0; j < 4; ++j) tile[r][c4 + j] = f2bf(v[j]);
  }
  __syncthreads();
#pragma unroll
  for (int i = 0; i < 4; ++i) {
    int idx = i * 256 + t;
    int r = idx >> 4;
    int c4 = (idx & 15) << 2;
    u16x4 v;
    v[0] = tile[c4 + 0][r];
    v[1] = tile[c4 + 1][r];
    v[2] = tile[c4 + 2][r];
    v[3] = tile[c4 + 3][r];
    *(u16x4*)&out[(size_t)(n0 + r) * K + k0 + c4] = v;
  }
}

// ------------- GEMM: C[M,N] = A[M,K] @ W[K,N] + bias, W transposed bf16 Wt[N,K] -------------
template <bool AF32, bool OF32>
__global__ __launch_bounds__(256) void gemm_bt_bias(const void* __restrict__ Av,
                                                    const u16* __restrict__ Wt,
                                                    const float* __restrict__ bias,
                                                    void* __restrict__ Cv,
                                                    int M, int N, int K) {
  __shared__ u16 lA[128 * 64];
  __shared__ u16 lB[128 * 64];
  int m0 = blockIdx.y * 128, n0 = blockIdx.x * 128;
  int t = threadIdx.x;
  int lane = t & 63, lq = lane & 15, hi = lane >> 4;
  int w = t >> 6, wm = w >> 1, wn = w & 1;

  f32x4 acc[4][4];
#pragma unroll
  for (int im = 0; im < 4; ++im)
#pragma unroll
    for (int in = 0; in < 4; ++in) acc[im][in] = (f32x4){0.f, 0.f, 0.f, 0.f};

  for (int k0 = 0; k0 < K; k0 += 64) {
    __syncthreads();
#pragma unroll
    for (int i = 0; i < 4; ++i) {
      int idx = i * 256 + t;
      int r = idx >> 3, c8 = (idx & 7) << 3;
      glds16(&Wt[(size_t)(n0 + r) * K + k0 + c8], &lB[idx * 8]);
    }
    if constexpr (AF32) {
      const float* A = (const float*)Av;
#pragma unroll
      for (int i = 0; i < 8; ++i) {
        int idx = i * 256 + t;
        int r = idx >> 4, c4 = (idx & 15) << 2;
        f32x4 av = *(const f32x4*)&A[(size_t)(m0 + r) * K + k0 + c4];
        s16x4 bv;
#pragma unroll
        for (int j = 0; j < 4; ++j) bv[j] = (short)f2bf(av[j]);
        *(s16x4*)&lA[r * 64 + c4] = bv;
      }
    } else {
      const u16* A = (const u16*)Av;
#pragma unroll
      for (int i = 0; i < 4; ++i) {
        int idx = i * 256 + t;
        int r = idx >> 3, c8 = (idx & 7) << 3;
        glds16(&A[(size_t)(m0 + r) * K + k0 + c8], &lA[idx * 8]);
      }
    }
    __syncthreads();
#pragma unroll
    for (int kk = 0; kk < 2; ++kk) {
      bf16x8 af[4], bfr[4];
#pragma unroll
      for (int im = 0; im < 4; ++im)
        af[im] = *(const bf16x8*)&lA[(wm * 64 + im * 16 + lq) * 64 + kk * 32 + hi * 8];
#pragma unroll
      for (int in = 0; in < 4; ++in)
        bfr[in] = *(const bf16x8*)&lB[(wn * 64 + in * 16 + lq) * 64 + kk * 32 + hi * 8];
#pragma unroll
      for (int im = 0; im < 4; ++im)
#pragma unroll
        for (int in = 0; in < 4; ++in)
          acc[im][in] = __builtin_amdgcn_mfma_f32_16x16x32_bf16(af[im], bfr[in], acc[im][in], 0, 0, 0);
    }
  }
#pragma unroll
  for (int im = 0; im < 4; ++im)
#pragma unroll
    for (int in = 0; in < 4; ++in) {
      int col = n0 + wn * 64 + in * 16 + lq;
      float bv = bias[col];
      int rbase = m0 + wm * 64 + im * 16 + hi * 4;
#pragma unroll
      for (int r = 0; r < 4; ++r) {
        float v = acc[im][in][r] + bv;
        if constexpr (OF32)
          ((float*)Cv)[(size_t)(rbase + r) * N + col] = v;
        else
          ((u16*)Cv)[(size_t)(rbase + r) * N + col] = f2bf(v);
      }
    }
}

// ------------- recon K: Kf[bh][s][dk] -------------
__global__ __launch_bounds__(256) void recon_k(const u16* __restrict__ L,
                                               const u16* __restrict__ WT,
                                               u16* __restrict__ out) {
  int bh = blockIdx.y, st = blockIdx.x;
  int b = bh >> 4, h = bh & 15;
  int t = threadIdx.x, w = t >> 6, lane = t & 63, lq = lane & 15, hi = lane >> 4;
  int s0 = st * 64 + w * 16;
  const u16* lrow = L + (size_t)(b * S_LEN + s0 + lq) * (NH * LDIM) + h * LDIM;
  bf16x8 a0 = *(const bf16x8*)&lrow[hi * 8];
  bf16x8 a1 = *(const bf16x8*)&lrow[32 + hi * 8];
  u16* obase = out + (size_t)bh * S_LEN * DKH;
#pragma unroll
  for (int fn = 0; fn < 8; ++fn) {
    const u16* wrow = WT + (size_t)(fn * 16 + lq) * LDIM;
    bf16x8 b0 = *(const bf16x8*)&wrow[hi * 8];
    bf16x8 b1 = *(const bf16x8*)&wrow[32 + hi * 8];
    f32x4 acc = (f32x4){0.f, 0.f, 0.f, 0.f};
    acc = __builtin_amdgcn_mfma_f32_16x16x32_bf16(a0, b0, acc, 0, 0, 0);
    acc = __builtin_amdgcn_mfma_f32_16x16x32_bf16(a1, b1, acc, 0, 0, 0);
#pragma unroll
    for (int r = 0; r < 4; ++r)
      obase[(size_t)(s0 + hi * 4 + r) * DKH + fn * 16 + lq] = f2bf(acc[r]);
  }
}

// ------------- recon V^T, k-slot-PERMUTED within each 32-s block -------------
// Vt'[dv][kblk*32 + hi*8 + j] = V[dv][kblk*32 + k],  k = (j>>2)*16 + hi*4 + (j&3)
__global__ __launch_bounds__(256) void recon_vt(const u16* __restrict__ L,
                                                const u16* __restrict__ WT,
                                                u16* __restrict__ out) {
  int bh = blockIdx.y, st = blockIdx.x;
  int b = bh >> 4, h = bh & 15;
  int t = threadIdx.x, w = t >> 6, lane = t & 63, lq = lane & 15, hi = lane >> 4;
  u16* obase = out + (size_t)bh * DKH * S_LEN;
  bf16x8 bfr[4][2];
#pragma unroll
  for (int fs = 0; fs < 4; ++fs) {
    const u16* lrow = L + (size_t)(b * S_LEN + st * 64 + fs * 16 + lq) * (NH * LDIM) + h * LDIM;
    bfr[fs][0] = *(const bf16x8*)&lrow[hi * 8];
    bfr[fs][1] = *(const bf16x8*)&lrow[32 + hi * 8];
  }
#pragma unroll
  for (int fd = 0; fd < 2; ++fd) {
    int dv0 = w * 32 + fd * 16;
    const u16* wrow = WT + (size_t)(dv0 + lq) * LDIM;
    bf16x8 a0 = *(const bf16x8*)&wrow[hi * 8];
    bf16x8 a1 = *(const bf16x8*)&wrow[32 + hi * 8];
#pragma unroll
    for (int fs = 0; fs < 4; ++fs) {
      f32x4 acc = (f32x4){0.f, 0.f, 0.f, 0.f};
      acc = __builtin_amdgcn_mfma_f32_16x16x32_bf16(a0, bfr[fs][0], acc, 0, 0, 0);
      acc = __builtin_amdgcn_mfma_f32_16x16x32_bf16(a1, bfr[fs][1], acc, 0, 0, 0);
      // MFMA D: col(s) = lq, row(dv) = hi*4+r.  s_global = st*64+fs*16+lq
      int kblk = st * 2 + (fs >> 1);
      int pos = (lq >> 2) * 8 + (fs & 1) * 4 + (lq & 3);
#pragma unroll
      for (int r = 0; r < 4; ++r)
        obase[(size_t)(dv0 + hi * 4 + r) * S_LEN + kblk * 32 + pos] = f2bf(acc[r]);
    }
  }
}

// ------------- flash attention v2: QBLK=128, qi=2, LDS-staged K/V double-buffered -------------
__global__ __launch_bounds__(256) void mla_attn2(const u16* __restrict__ Qp,
                                                 const u16* __restrict__ Kf,
                                                 const u16* __restrict__ Vt,
                                                 u16* __restrict__ O) {
  __shared__ u16 smem[32768];  // 2x K[64][128] + 2x V[128][64]; epilogue reuses [128][128]
  int Lb = blockIdx.x + blockIdx.y * 8;
  int xcd = Lb & 7, ii = Lb >> 3;
  int bh = xcd * 4 + (ii & 3);   // XCD-local bh clustering (4 bh per XCD -> K/V fits one L2)
  int pr = ii >> 2;              // pair index 0..7
  int b = bh >> 4, h = bh & 15;
  int t = threadIdx.x, w = t >> 6, lane = t & 63, lq = lane & 15, hi = lane >> 4;
  int lq7 = lq & 7;

  const u16* Kb = Kf + (size_t)bh * S_LEN * DKH;
  const u16* Vb = Vt + (size_t)bh * DKH * S_LEN;
  const float scale = 0.08838834764831845f;

  auto stage = [&](int buf, int k0) {
    u16* lK = smem + buf * 8192;
    u16* lV = smem + 16384 + buf * 8192;
#pragma unroll
    for (int i = 0; i < 4; ++i) {
      int idx = i * 256 + t;
      int row = idx >> 4, c16 = idx & 15;
      glds16(Kb + (size_t)(k0 + row) * DKH + ((c16 ^ (row & 7)) << 3), lK + idx * 8);
    }
#pragma unroll
    for (int i = 0; i < 4; ++i) {
      int idx = i * 256 + t;
      int row = idx >> 3, c16 = idx & 7;
      glds16(Vb + (size_t)row * S_LEN + k0 + ((c16 ^ (row & 7)) << 3), lV + idx * 8);
    }
  };

  for (int pi = 0; pi < 2; ++pi) {
    int qsup = pi ? (15 - pr) : pr;
    int qb = qsup * 128;
    int nt = qsup * 2 + 2;
    int kmax = qb + w * 32 + 32;

    bf16x8 qf[2][4];
#pragma unroll
    for (int qi = 0; qi < 2; ++qi) {
      const u16* Qrow = Qp + (size_t)(b * S_LEN + qb + w * 32 + qi * 16 + lq) * 2048 + h * 128;
#pragma unroll
      for (int d0 = 0; d0 < 4; ++d0) qf[qi][d0] = *(const bf16x8*)&Qrow[d0 * 32 + hi * 8];
    }

    f32x4 acc[2][8];
#pragma unroll
    for (int qi = 0; qi < 2; ++qi)
#pragma unroll
      for (int f = 0; f < 8; ++f) acc[qi][f] = (f32x4){0.f, 0.f, 0.f, 0.f};
    float m[2] = {-1e30f, -1e30f}, l[2] = {0.f, 0.f};

    stage(0, 0);
    __syncthreads();
    for (int tt = 0; tt < nt; ++tt) {
      int cur = tt & 1;
      if (tt + 1 < nt) stage(cur ^ 1, (tt + 1) * 64);
      int k0 = tt * 64;
      if (k0 < kmax) {
        const u16* lK = smem + cur * 8192;
        const u16* lV = smem + 16384 + cur * 8192;
        f32x4 sc[2][4];
#pragma unroll
        for (int qi = 0; qi < 2; ++qi)
#pragma unroll
          for (int kf = 0; kf < 4; ++kf) sc[qi][kf] = (f32x4){0.f, 0.f, 0.f, 0.f};
#pragma unroll
        for (int kf = 0; kf < 4; ++kf) {
          const u16* kr = lK + (kf * 16 + lq) * 128;
#pragma unroll
          for (int d0 = 0; d0 < 4; ++d0) {
            bf16x8 af = *(const bf16x8*)&kr[(((d0 << 2) + hi) ^ lq7) << 3];
            sc[0][kf] = __builtin_amdgcn_mfma_f32_16x16x32_bf16(af, qf[0][d0], sc[0][kf], 0, 0, 0);
            sc[1][kf] = __builtin_amdgcn_mfma_f32_16x16x32_bf16(af, qf[1][d0], sc[1][kf], 0, 0, 0);
          }
        }
        bf16x8 pb[2][2];
#pragma unroll
        for (int qi = 0; qi < 2; ++qi) {
          int qfmin = qb + w * 32 + qi * 16;
          int q = qfmin + lq;
          float sv[16];
#pragma unroll
          for (int kf = 0; kf < 4; ++kf)
#pragma unroll
            for (int r = 0; r < 4; ++r) sv[kf * 4 + r] = sc[qi][kf][r] * scale;
          if (k0 + 63 > qfmin) {
#pragma unroll
            for (int kf = 0; kf < 4; ++kf)
#pragma unroll
              for (int r = 0; r < 4; ++r)
                if (k0 + kf * 16 + hi * 4 + r > q) sv[kf * 4 + r] = -1e30f;
          }
          float tm = sv[0];
#pragma unroll
          for (int j = 1; j < 16; ++j) tm = fmaxf(tm, sv[j]);
          tm = fmaxf(tm, __shfl_xor(tm, 16));
          tm = fmaxf(tm, __shfl_xor(tm, 32));
          float mnew = fmaxf(m[qi], tm);
          float alpha = __expf(m[qi] - mnew);
          float p[16], ps = 0.f;
#pragma unroll
          for (int j = 0; j < 16; ++j) { p[j] = __expf(sv[j] - mnew); ps += p[j]; }
          ps += __shfl_xor(ps, 16);
          ps += __shfl_xor(ps, 32);
          l[qi] = l[qi] * alpha + ps;
          m[qi] = mnew;
#pragma unroll
          for (int f = 0; f < 8; ++f) {
            acc[qi][f][0] *= alpha; acc[qi][f][1] *= alpha;
            acc[qi][f][2] *= alpha; acc[qi][f][3] *= alpha;
          }
#pragma unroll
          for (int ks = 0; ks < 2; ++ks)
#pragma unroll
            for (int j = 0; j < 8; ++j)
              pb[qi][ks][j] = (short)f2bf(p[(ks * 2 + (j >> 2)) * 4 + (j & 3)]);
        }
#pragma unroll
        for (int f = 0; f < 8; ++f) {
          const u16* vr = lV + (f * 16 + lq) * 64;
#pragma unroll
          for (int ks = 0; ks < 2; ++ks) {
            bf16x8 va = *(const bf16x8*)&vr[(((ks << 2) + hi) ^ lq7) << 3];
            acc[0][f] = __builtin_amdgcn_mfma_f32_16x16x32_bf16(va, pb[0][ks], acc[0][f], 0, 0, 0);
            acc[1][f] = __builtin_amdgcn_mfma_f32_16x16x32_bf16(va, pb[1][ks], acc[1][f], 0, 0, 0);
          }
        }
      }
      __syncthreads();
    }
    // epilogue: swizzled O^T -> LDS -> coalesced stores
#pragma unroll
    for (int qi = 0; qi < 2; ++qi) {
      float inv = 1.f / l[qi];
      int qloc = w * 32 + qi * 16 + lq;
#pragma unroll
      for (int f = 0; f < 8; ++f)
#pragma unroll
        for (int r = 0; r < 4; ++r) {
          int col = f * 16 + hi * 4 + r;
          smem[qloc * 128 + (((col >> 3) ^ lq7) << 3) + (col & 7)] = f2bf(acc[qi][f][r] * inv);
        }
    }
    __syncthreads();
#pragma unroll
    for (int i = 0; i < 8; ++i) {
      int cid = i * 256 + t;
      int q = cid >> 4, ch = cid & 15;
      bf16x8 v = *(const bf16x8*)&smem[q * 128 + ((ch ^ (q & 7)) << 3)];
      *(bf16x8*)&O[(size_t)(b * S_LEN + qb + q) * 2048 + h * 128 + (ch << 3)] = v;
    }
    __syncthreads();
  }
}

extern "C" void kernel_launch(void* const* d_in, const int* in_sizes, int n_in,
                              void* d_out, int out_size, void* d_ws, size_t ws_size,
                              hipStream_t stream) {
  const float* queries = (const float*)d_in[0];
  const float* keys    = (const float*)d_in[1];
  const float* values  = (const float*)d_in[2];
  const float* Wq      = (const float*)d_in[3];
  const float* bq      = (const float*)d_in[4];
  const float* Wlk     = (const float*)d_in[5];
  const float* blk     = (const float*)d_in[6];
  const float* Wlv     = (const float*)d_in[7];
  const float* blv     = (const float*)d_in[8];
  const float* Wkr     = (const float*)d_in[9];
  const float* Wvr     = (const float*)d_in[10];
  const float* Wout    = (const float*)d_in[11];
  const float* bout    = (const float*)d_in[12];

  u16* ws = (u16*)d_ws;
  u16* WqT   = ws; ws += (size_t)2048 * 2048;
  u16* WlkT  = ws; ws += (size_t)1024 * 2048;
  u16* WlvT  = ws; ws += (size_t)1024 * 2048;
  u16* WoutT = ws; ws += (size_t)2048 * 2048;
  u16* WkrT  = ws; ws += 128 * 64;
  u16* WvrT  = ws; ws += 128 * 64;
  u16* Qp    = ws; ws += (size_t)4096 * 2048;
  u16* LKb   = ws; ws += (size_t)4096 * 1024;
  u16* LVb   = ws; ws += (size_t)4096 * 1024;
  u16* Kfb   = ws; ws += (size_t)4096 * 2048;
  u16* Vtb   = ws; ws += (size_t)4096 * 2048;
  u16* Ob    = ws; ws += (size_t)4096 * 2048;

  dim3 blk256(256);
  transpose_f32_bf16<<<dim3(32, 32), blk256, 0, stream>>>(Wq, WqT, 2048, 2048);
  transpose_f32_bf16<<<dim3(16, 32), blk256, 0, stream>>>(Wlk, WlkT, 2048, 1024);
  transpose_f32_bf16<<<dim3(16, 32), blk256, 0, stream>>>(Wlv, WlvT, 2048, 1024);
  transpose_f32_bf16<<<dim3(32, 32), blk256, 0, stream>>>(Wout, WoutT, 2048, 2048);
  transpose_f32_bf16<<<dim3(2, 1), blk256, 0, stream>>>(Wkr, WkrT, 64, 128);
  transpose_f32_bf16<<<dim3(2, 1), blk256, 0, stream>>>(Wvr, WvrT, 64, 128);

  gemm_bt_bias<true, false><<<dim3(16, 32), blk256, 0, stream>>>(queries, WqT, bq, Qp, 4096, 2048, 2048);
  gemm_bt_bias<true, false><<<dim3(8, 32), blk256, 0, stream>>>(keys, WlkT, blk, LKb, 4096, 1024, 2048);
  gemm_bt_bias<true, false><<<dim3(8, 32), blk256, 0, stream>>>(values, WlvT, blv, LVb, 4096, 1024, 2048);

  recon_k<<<dim3(32, 32), blk256, 0, stream>>>(LKb, WkrT, Kfb);
  recon_vt<<<dim3(32, 32), blk256, 0, stream>>>(LVb, WvrT, Vtb);

  mla_attn2<<<dim3(8, 32), blk256, 0, stream>>>(Qp, Kfb, Vtb, Ob);

  gemm_bt_bias<false, true><<<dim3(16, 32), blk256, 0, stream>>>(Ob, WoutT, bout, (float*)d_out, 4096, 2048, 2048);
}

// Round 4
// 352.240 us; speedup vs baseline: 2.7511x; 1.1307x over previous
//
#include <hip/hip_runtime.h>

#define S_LEN 2048
#define NH 16
#define DKH 128
#define LDIM 64

typedef unsigned short u16;
typedef __attribute__((ext_vector_type(8))) short bf16x8;
typedef __attribute__((ext_vector_type(4))) short s16x4;
typedef __attribute__((ext_vector_type(4))) unsigned short u16x4;
typedef __attribute__((ext_vector_type(4))) unsigned int u32x4;
typedef __attribute__((ext_vector_type(4))) float f32x4;

__device__ __forceinline__ u16 f2bf(float f) {
  union { float f; unsigned int i; } x; x.f = f;
  unsigned int r = x.i + 0x7FFFu + ((x.i >> 16) & 1u);
  return (u16)(r >> 16);
}
__device__ __forceinline__ unsigned pk2(float lo, float hi) {
  unsigned r;
  asm("v_cvt_pk_bf16_f32 %0, %1, %2" : "=v"(r) : "v"(lo), "v"(hi));
  return r;
}
__device__ __forceinline__ void glds16(const void* g, void* l) {
  __builtin_amdgcn_global_load_lds((const __attribute__((address_space(1))) void*)g,
                                   (__attribute__((address_space(3))) void*)l, 16, 0, 0);
}

// ---------------- cast fp32 -> bf16, 8 elems/thread ----------------
__global__ __launch_bounds__(256) void cast_f32_bf16(const float* __restrict__ in,
                                                     u16* __restrict__ out) {
  size_t i = ((size_t)blockIdx.x * 256 + threadIdx.x) * 8;
  f32x4 a = *(const f32x4*)&in[i];
  f32x4 b = *(const f32x4*)&in[i + 4];
  u32x4 o;
  o[0] = pk2(a[0], a[1]);
  o[1] = pk2(a[2], a[3]);
  o[2] = pk2(b[0], b[1]);
  o[3] = pk2(b[2], b[3]);
  *(u32x4*)&out[i] = o;
}

// ---------------- transpose+cast: in [K,N] fp32 -> out [N,K] bf16 ----------------
__global__ __launch_bounds__(256) void transpose_f32_bf16(const float* __restrict__ in,
                                                          u16* __restrict__ out,
                                                          int K, int N) {
  __shared__ u16 tile[64][72];
  int k0 = blockIdx.y * 64, n0 = blockIdx.x * 64;
  int t = threadIdx.x;
#pragma unroll
  for (int i = 0; i < 4; ++i) {
    int idx = i * 256 + t;
    int r = idx >> 4;
    int c4 = (idx & 15) << 2;
    f32x4 v = *(const f32x4*)&in[(size_t)(k0 + r) * N + n0 + c4];
#pragma unroll
    for (int j = 0; j < 4; ++j) tile[r][c4 + j] = f2bf(v[j]);
  }
  __syncthreads();
#pragma unroll
  for (int i = 0; i < 4; ++i) {
    int idx = i * 256 + t;
    int r = idx >> 4;
    int c4 = (idx & 15) << 2;
    u16x4 v;
    v[0] = tile[c4 + 0][r];
    v[1] = tile[c4 + 1][r];
    v[2] = tile[c4 + 2][r];
    v[3] = tile[c4 + 3][r];
    *(u16x4*)&out[(size_t)(n0 + r) * K + k0 + c4] = v;
  }
}

// ------------- GEMM: C[M,N] = A[M,K](bf16) @ W[K,N] + bias, W transposed bf16 Wt[N,K] -------------
template <bool OF32>
__global__ __launch_bounds__(256) void gemm_bt_bias(const u16* __restrict__ A,
                                                    const u16* __restrict__ Wt,
                                                    const float* __restrict__ bias,
                                                    void* __restrict__ Cv,
                                                    int M, int N, int K) {
  __shared__ u16 lA[128 * 64];
  __shared__ u16 lB[128 * 64];
  int m0 = blockIdx.y * 128, n0 = blockIdx.x * 128;
  int t = threadIdx.x;
  int lane = t & 63, lq = lane & 15, hi = lane >> 4;
  int w = t >> 6, wm = w >> 1, wn = w & 1;

  f32x4 acc[4][4];
#pragma unroll
  for (int im = 0; im < 4; ++im)
#pragma unroll
    for (int in = 0; in < 4; ++in) acc[im][in] = (f32x4){0.f, 0.f, 0.f, 0.f};

  for (int k0 = 0; k0 < K; k0 += 64) {
    __syncthreads();
#pragma unroll
    for (int i = 0; i < 4; ++i) {
      int idx = i * 256 + t;
      int r = idx >> 3, c8 = (idx & 7) << 3;
      glds16(&Wt[(size_t)(n0 + r) * K + k0 + c8], &lB[idx * 8]);
    }
#pragma unroll
    for (int i = 0; i < 4; ++i) {
      int idx = i * 256 + t;
      int r = idx >> 3, c8 = (idx & 7) << 3;
      glds16(&A[(size_t)(m0 + r) * K + k0 + c8], &lA[idx * 8]);
    }
    __syncthreads();
#pragma unroll
    for (int kk = 0; kk < 2; ++kk) {
      bf16x8 af[4], bfr[4];
#pragma unroll
      for (int im = 0; im < 4; ++im)
        af[im] = *(const bf16x8*)&lA[(wm * 64 + im * 16 + lq) * 64 + kk * 32 + hi * 8];
#pragma unroll
      for (int in = 0; in < 4; ++in)
        bfr[in] = *(const bf16x8*)&lB[(wn * 64 + in * 16 + lq) * 64 + kk * 32 + hi * 8];
#pragma unroll
      for (int im = 0; im < 4; ++im)
#pragma unroll
        for (int in = 0; in < 4; ++in)
          acc[im][in] = __builtin_amdgcn_mfma_f32_16x16x32_bf16(af[im], bfr[in], acc[im][in], 0, 0, 0);
    }
  }
#pragma unroll
  for (int im = 0; im < 4; ++im)
#pragma unroll
    for (int in = 0; in < 4; ++in) {
      int col = n0 + wn * 64 + in * 16 + lq;
      float bv = bias[col];
      int rbase = m0 + wm * 64 + im * 16 + hi * 4;
#pragma unroll
      for (int r = 0; r < 4; ++r) {
        float v = acc[im][in][r] + bv;
        if constexpr (OF32)
          ((float*)Cv)[(size_t)(rbase + r) * N + col] = v;
        else
          ((u16*)Cv)[(size_t)(rbase + r) * N + col] = f2bf(v);
      }
    }
}

// ------------- recon K: Kf[bh][s][dk] -------------
__global__ __launch_bounds__(256) void recon_k(const u16* __restrict__ L,
                                               const u16* __restrict__ WT,
                                               u16* __restrict__ out) {
  int bh = blockIdx.y, st = blockIdx.x;
  int b = bh >> 4, h = bh & 15;
  int t = threadIdx.x, w = t >> 6, lane = t & 63, lq = lane & 15, hi = lane >> 4;
  int s0 = st * 64 + w * 16;
  const u16* lrow = L + (size_t)(b * S_LEN + s0 + lq) * (NH * LDIM) + h * LDIM;
  bf16x8 a0 = *(const bf16x8*)&lrow[hi * 8];
  bf16x8 a1 = *(const bf16x8*)&lrow[32 + hi * 8];
  u16* obase = out + (size_t)bh * S_LEN * DKH;
#pragma unroll
  for (int fn = 0; fn < 8; ++fn) {
    const u16* wrow = WT + (size_t)(fn * 16 + lq) * LDIM;
    bf16x8 b0 = *(const bf16x8*)&wrow[hi * 8];
    bf16x8 b1 = *(const bf16x8*)&wrow[32 + hi * 8];
    f32x4 acc = (f32x4){0.f, 0.f, 0.f, 0.f};
    acc = __builtin_amdgcn_mfma_f32_16x16x32_bf16(a0, b0, acc, 0, 0, 0);
    acc = __builtin_amdgcn_mfma_f32_16x16x32_bf16(a1, b1, acc, 0, 0, 0);
#pragma unroll
    for (int r = 0; r < 4; ++r)
      obase[(size_t)(s0 + hi * 4 + r) * DKH + fn * 16 + lq] = f2bf(acc[r]);
  }
}

// ------------- recon V^T, k-slot-PERMUTED within each 32-s block -------------
__global__ __launch_bounds__(256) void recon_vt(const u16* __restrict__ L,
                                                const u16* __restrict__ WT,
                                                u16* __restrict__ out) {
  int bh = blockIdx.y, st = blockIdx.x;
  int b = bh >> 4, h = bh & 15;
  int t = threadIdx.x, w = t >> 6, lane = t & 63, lq = lane & 15, hi = lane >> 4;
  u16* obase = out + (size_t)bh * DKH * S_LEN;
  bf16x8 bfr[4][2];
#pragma unroll
  for (int fs = 0; fs < 4; ++fs) {
    const u16* lrow = L + (size_t)(b * S_LEN + st * 64 + fs * 16 + lq) * (NH * LDIM) + h * LDIM;
    bfr[fs][0] = *(const bf16x8*)&lrow[hi * 8];
    bfr[fs][1] = *(const bf16x8*)&lrow[32 + hi * 8];
  }
#pragma unroll
  for (int fd = 0; fd < 2; ++fd) {
    int dv0 = w * 32 + fd * 16;
    const u16* wrow = WT + (size_t)(dv0 + lq) * LDIM;
    bf16x8 a0 = *(const bf16x8*)&wrow[hi * 8];
    bf16x8 a1 = *(const bf16x8*)&wrow[32 + hi * 8];
#pragma unroll
    for (int fs = 0; fs < 4; ++fs) {
      f32x4 acc = (f32x4){0.f, 0.f, 0.f, 0.f};
      acc = __builtin_amdgcn_mfma_f32_16x16x32_bf16(a0, bfr[fs][0], acc, 0, 0, 0);
      acc = __builtin_amdgcn_mfma_f32_16x16x32_bf16(a1, bfr[fs][1], acc, 0, 0, 0);
      int kblk = st * 2 + (fs >> 1);
      int pos = (lq >> 2) * 8 + (fs & 1) * 4 + (lq & 3);
#pragma unroll
      for (int r = 0; r < 4; ++r)
        obase[(size_t)(dv0 + hi * 4 + r) * S_LEN + kblk * 32 + pos] = f2bf(acc[r]);
    }
  }
}

// ------------- flash attention v3: 512 blocks (2/CU), defer-max, pk-cvt, setprio -------------
__global__ __launch_bounds__(256) void mla_attn3(const u16* __restrict__ Qp,
                                                 const u16* __restrict__ Kf,
                                                 const u16* __restrict__ Vt,
                                                 u16* __restrict__ O) {
  __shared__ u16 smem[32768];
  int Lb = blockIdx.x + blockIdx.y * 8;
  int half = Lb >> 8;
  int i0 = Lb & 255;
  int xcd = i0 & 7, ii = i0 >> 3;
  int bh = xcd * 4 + (ii & 3);
  int pr = ii >> 2;
  int qsup = half ? (15 - pr) : pr;
  int b = bh >> 4, h = bh & 15;
  int t = threadIdx.x, w = t >> 6, lane = t & 63, lq = lane & 15, hi = lane >> 4;
  int lq7 = lq & 7;

  const u16* Kb = Kf + (size_t)bh * S_LEN * DKH;
  const u16* Vb = Vt + (size_t)bh * DKH * S_LEN;
  const float scale = 0.08838834764831845f;

  auto stage = [&](int buf, int k0) {
    u16* lK = smem + buf * 8192;
    u16* lV = smem + 16384 + buf * 8192;
#pragma unroll
    for (int i = 0; i < 4; ++i) {
      int idx = i * 256 + t;
      int row = idx >> 4, c16 = idx & 15;
      glds16(Kb + (size_t)(k0 + row) * DKH + ((c16 ^ (row & 7)) << 3), lK + idx * 8);
    }
#pragma unroll
    for (int i = 0; i < 4; ++i) {
      int idx = i * 256 + t;
      int row = idx >> 3, c16 = idx & 7;
      glds16(Vb + (size_t)row * S_LEN + k0 + ((c16 ^ (row & 7)) << 3), lV + idx * 8);
    }
  };

  int qb = qsup * 128;
  int nt = qsup * 2 + 2;
  int kmax = qb + w * 32 + 32;

  bf16x8 qf[2][4];
#pragma unroll
  for (int qi = 0; qi < 2; ++qi) {
    const u16* Qrow = Qp + (size_t)(b * S_LEN + qb + w * 32 + qi * 16 + lq) * 2048 + h * 128;
#pragma unroll
    for (int d0 = 0; d0 < 4; ++d0) qf[qi][d0] = *(const bf16x8*)&Qrow[d0 * 32 + hi * 8];
  }

  f32x4 acc[2][8];
#pragma unroll
  for (int qi = 0; qi < 2; ++qi)
#pragma unroll
    for (int f = 0; f < 8; ++f) acc[qi][f] = (f32x4){0.f, 0.f, 0.f, 0.f};
  float m[2] = {-1e30f, -1e30f}, l[2] = {0.f, 0.f};

  stage(0, 0);
  __syncthreads();
  for (int tt = 0; tt < nt; ++tt) {
    int cur = tt & 1;
    if (tt + 1 < nt) stage(cur ^ 1, (tt + 1) * 64);
    int k0 = tt * 64;
    if (k0 < kmax) {
      const u16* lK = smem + cur * 8192;
      const u16* lV = smem + 16384 + cur * 8192;
      f32x4 sc[2][4];
#pragma unroll
      for (int qi = 0; qi < 2; ++qi)
#pragma unroll
        for (int kf = 0; kf < 4; ++kf) sc[qi][kf] = (f32x4){0.f, 0.f, 0.f, 0.f};
      __builtin_amdgcn_s_setprio(1);
#pragma unroll
      for (int kf = 0; kf < 4; ++kf) {
        const u16* kr = lK + (kf * 16 + lq) * 128;
#pragma unroll
        for (int d0 = 0; d0 < 4; ++d0) {
          bf16x8 af = *(const bf16x8*)&kr[(((d0 << 2) + hi) ^ lq7) << 3];
          sc[0][kf] = __builtin_amdgcn_mfma_f32_16x16x32_bf16(af, qf[0][d0], sc[0][kf], 0, 0, 0);
          sc[1][kf] = __builtin_amdgcn_mfma_f32_16x16x32_bf16(af, qf[1][d0], sc[1][kf], 0, 0, 0);
        }
      }
      __builtin_amdgcn_s_setprio(0);
      bf16x8 pb[2][2];
#pragma unroll
      for (int qi = 0; qi < 2; ++qi) {
        int qfmin = qb + w * 32 + qi * 16;
        int q = qfmin + lq;
        float sv[16];
#pragma unroll
        for (int kf = 0; kf < 4; ++kf)
#pragma unroll
          for (int r = 0; r < 4; ++r) sv[kf * 4 + r] = sc[qi][kf][r] * scale;
        if (k0 + 63 > qfmin) {
#pragma unroll
          for (int kf = 0; kf < 4; ++kf)
#pragma unroll
            for (int r = 0; r < 4; ++r)
              if (k0 + kf * 16 + hi * 4 + r > q) sv[kf * 4 + r] = -1e30f;
        }
        float tm = sv[0];
#pragma unroll
        for (int j = 1; j < 16; ++j) tm = fmaxf(tm, sv[j]);
        tm = fmaxf(tm, __shfl_xor(tm, 16));
        tm = fmaxf(tm, __shfl_xor(tm, 32));
        float p[16], ps = 0.f;
        if (__all(tm <= m[qi] + 8.f)) {
          // defer-max: keep old m, no rescale (P bounded by e^8)
#pragma unroll
          for (int j = 0; j < 16; ++j) { p[j] = __expf(sv[j] - m[qi]); ps += p[j]; }
          ps += __shfl_xor(ps, 16);
          ps += __shfl_xor(ps, 32);
          l[qi] += ps;
        } else {
          float mnew = fmaxf(m[qi], tm);
          float alpha = __expf(m[qi] - mnew);
#pragma unroll
          for (int j = 0; j < 16; ++j) { p[j] = __expf(sv[j] - mnew); ps += p[j]; }
          ps += __shfl_xor(ps, 16);
          ps += __shfl_xor(ps, 32);
          l[qi] = l[qi] * alpha + ps;
          m[qi] = mnew;
#pragma unroll
          for (int f = 0; f < 8; ++f) {
            acc[qi][f][0] *= alpha; acc[qi][f][1] *= alpha;
            acc[qi][f][2] *= alpha; acc[qi][f][3] *= alpha;
          }
        }
        // pb[ks][j] = p[8*ks + j]  -> pack pairs with v_cvt_pk_bf16_f32
#pragma unroll
        for (int ks = 0; ks < 2; ++ks) {
          union { u32x4 u; bf16x8 v; } pu;
#pragma unroll
          for (int wd = 0; wd < 4; ++wd) pu.u[wd] = pk2(p[ks * 8 + 2 * wd], p[ks * 8 + 2 * wd + 1]);
          pb[qi][ks] = pu.v;
        }
      }
      __builtin_amdgcn_s_setprio(1);
#pragma unroll
      for (int f = 0; f < 8; ++f) {
        const u16* vr = lV + (f * 16 + lq) * 64;
#pragma unroll
        for (int ks = 0; ks < 2; ++ks) {
          bf16x8 va = *(const bf16x8*)&vr[(((ks << 2) + hi) ^ lq7) << 3];
          acc[0][f] = __builtin_amdgcn_mfma_f32_16x16x32_bf16(va, pb[0][ks], acc[0][f], 0, 0, 0);
          acc[1][f] = __builtin_amdgcn_mfma_f32_16x16x32_bf16(va, pb[1][ks], acc[1][f], 0, 0, 0);
        }
      }
      __builtin_amdgcn_s_setprio(0);
    }
    __syncthreads();
  }
  // epilogue: swizzled O^T -> LDS -> coalesced stores
#pragma unroll
  for (int qi = 0; qi < 2; ++qi) {
    float inv = 1.f / l[qi];
    int qloc = w * 32 + qi * 16 + lq;
#pragma unroll
    for (int f = 0; f < 8; ++f)
#pragma unroll
      for (int r = 0; r < 4; ++r) {
        int col = f * 16 + hi * 4 + r;
        smem[qloc * 128 + (((col >> 3) ^ lq7) << 3) + (col & 7)] = f2bf(acc[qi][f][r] * inv);
      }
  }
  __syncthreads();
#pragma unroll
  for (int i = 0; i < 8; ++i) {
    int cid = i * 256 + t;
    int q = cid >> 4, ch = cid & 15;
    bf16x8 v = *(const bf16x8*)&smem[q * 128 + ((ch ^ (q & 7)) << 3)];
    *(bf16x8*)&O[(size_t)(b * S_LEN + qb + q) * 2048 + h * 128 + (ch << 3)] = v;
  }
}

extern "C" void kernel_launch(void* const* d_in, const int* in_sizes, int n_in,
                              void* d_out, int out_size, void* d_ws, size_t ws_size,
                              hipStream_t stream) {
  const float* queries = (const float*)d_in[0];
  const float* keys    = (const float*)d_in[1];
  const float* values  = (const float*)d_in[2];
  const float* Wq      = (const float*)d_in[3];
  const float* bq      = (const float*)d_in[4];
  const float* Wlk     = (const float*)d_in[5];
  const float* blk     = (const float*)d_in[6];
  const float* Wlv     = (const float*)d_in[7];
  const float* blv     = (const float*)d_in[8];
  const float* Wkr     = (const float*)d_in[9];
  const float* Wvr     = (const float*)d_in[10];
  const float* Wout    = (const float*)d_in[11];
  const float* bout    = (const float*)d_in[12];

  u16* ws = (u16*)d_ws;
  u16* WqT   = ws; ws += (size_t)2048 * 2048;
  u16* WlkT  = ws; ws += (size_t)1024 * 2048;
  u16* WlvT  = ws; ws += (size_t)1024 * 2048;
  u16* WoutT = ws; ws += (size_t)2048 * 2048;
  u16* WkrT  = ws; ws += 128 * 64;
  u16* WvrT  = ws; ws += 128 * 64;
  u16* Qp    = ws; ws += (size_t)4096 * 2048;
  u16* LKb   = ws; ws += (size_t)4096 * 1024;
  u16* LVb   = ws; ws += (size_t)4096 * 1024;
  u16* Qin   = ws; ws += (size_t)4096 * 2048;
  u16* Kin   = ws; ws += (size_t)4096 * 2048;
  u16* Vin   = ws; ws += (size_t)4096 * 2048;
  // aliases (strict same-stream ordering makes these safe):
  u16* Kfb = Kin;  // recon_k writes after LK-GEMM consumed Kin
  u16* Vtb = Vin;  // recon_vt writes after LV-GEMM consumed Vin
  u16* Ob  = Qin;  // attn writes after Q-GEMM consumed Qin

  dim3 blk256(256);
  cast_f32_bf16<<<dim3(4096), blk256, 0, stream>>>(queries, Qin);
  cast_f32_bf16<<<dim3(4096), blk256, 0, stream>>>(keys, Kin);
  cast_f32_bf16<<<dim3(4096), blk256, 0, stream>>>(values, Vin);

  transpose_f32_bf16<<<dim3(32, 32), blk256, 0, stream>>>(Wq, WqT, 2048, 2048);
  transpose_f32_bf16<<<dim3(16, 32), blk256, 0, stream>>>(Wlk, WlkT, 2048, 1024);
  transpose_f32_bf16<<<dim3(16, 32), blk256, 0, stream>>>(Wlv, WlvT, 2048, 1024);
  transpose_f32_bf16<<<dim3(32, 32), blk256, 0, stream>>>(Wout, WoutT, 2048, 2048);
  transpose_f32_bf16<<<dim3(2, 1), blk256, 0, stream>>>(Wkr, WkrT, 64, 128);
  transpose_f32_bf16<<<dim3(2, 1), blk256, 0, stream>>>(Wvr, WvrT, 64, 128);

  gemm_bt_bias<false><<<dim3(16, 32), blk256, 0, stream>>>(Qin, WqT, bq, Qp, 4096, 2048, 2048);
  gemm_bt_bias<false><<<dim3(8, 32), blk256, 0, stream>>>(Kin, WlkT, blk, LKb, 4096, 1024, 2048);
  gemm_bt_bias<false><<<dim3(8, 32), blk256, 0, stream>>>(Vin, WlvT, blv, LVb, 4096, 1024, 2048);

  recon_k<<<dim3(32, 32), blk256, 0, stream>>>(LKb, WkrT, Kfb);
  recon_vt<<<dim3(32, 32), blk256, 0, stream>>>(LVb, WvrT, Vtb);

  mla_attn3<<<dim3(8, 64), blk256, 0, stream>>>(Qp, Kfb, Vtb, Ob);

  gemm_bt_bias<true><<<dim3(16, 32), blk256, 0, stream>>>(Ob, WoutT, bout, (float*)d_out, 4096, 2048, 2048);
}

// Round 5
// 299.618 us; speedup vs baseline: 3.2343x; 1.1756x over previous
//
#include <hip/hip_runtime.h>

#define S_LEN 2048
#define NH 16

typedef unsigned short u16;
typedef __attribute__((ext_vector_type(8))) short bf16x8;
typedef __attribute__((ext_vector_type(4))) short s16x4;
typedef __attribute__((ext_vector_type(4))) unsigned short u16x4;
typedef __attribute__((ext_vector_type(4))) unsigned int u32x4;
typedef __attribute__((ext_vector_type(4))) float f32x4;

__device__ __forceinline__ u16 f2bf(float f) {
  union { float f; unsigned int i; } x; x.f = f;
  unsigned int r = x.i + 0x7FFFu + ((x.i >> 16) & 1u);
  return (u16)(r >> 16);
}
__device__ __forceinline__ unsigned pk2(float lo, float hi) {
  unsigned r;
  asm("v_cvt_pk_bf16_f32 %0, %1, %2" : "=v"(r) : "v"(lo), "v"(hi));
  return r;
}
__device__ __forceinline__ void glds16(const void* g, void* l) {
  __builtin_amdgcn_global_load_lds((const __attribute__((address_space(1))) void*)g,
                                   (__attribute__((address_space(3))) void*)l, 16, 0, 0);
}

// ---------------- cast fp32 -> bf16, 8 elems/thread ----------------
__global__ __launch_bounds__(256) void cast_f32_bf16(const float* __restrict__ in,
                                                     u16* __restrict__ out) {
  size_t i = ((size_t)blockIdx.x * 256 + threadIdx.x) * 8;
  f32x4 a = *(const f32x4*)&in[i];
  f32x4 b = *(const f32x4*)&in[i + 4];
  u32x4 o;
  o[0] = pk2(a[0], a[1]);
  o[1] = pk2(a[2], a[3]);
  o[2] = pk2(b[0], b[1]);
  o[3] = pk2(b[2], b[3]);
  *(u32x4*)&out[i] = o;
}

// ---------------- transpose+cast: in [K,N] fp32 -> out [N,K] bf16 ----------------
__global__ __launch_bounds__(256) void transpose_f32_bf16(const float* __restrict__ in,
                                                          u16* __restrict__ out,
                                                          int K, int N) {
  __shared__ u16 tile[64][72];
  int k0 = blockIdx.y * 64, n0 = blockIdx.x * 64;
  int t = threadIdx.x;
#pragma unroll
  for (int i = 0; i < 4; ++i) {
    int idx = i * 256 + t;
    int r = idx >> 4;
    int c4 = (idx & 15) << 2;
    f32x4 v = *(const f32x4*)&in[(size_t)(k0 + r) * N + n0 + c4];
#pragma unroll
    for (int j = 0; j < 4; ++j) tile[r][c4 + j] = f2bf(v[j]);
  }
  __syncthreads();
#pragma unroll
  for (int i = 0; i < 4; ++i) {
    int idx = i * 256 + t;
    int r = idx >> 4;
    int c4 = (idx & 15) << 2;
    u16x4 v;
    v[0] = tile[c4 + 0][r];
    v[1] = tile[c4 + 1][r];
    v[2] = tile[c4 + 2][r];
    v[3] = tile[c4 + 3][r];
    *(u16x4*)&out[(size_t)(n0 + r) * K + k0 + c4] = v;
  }
}

// ------------- absorb_q: Wq2T[h*64+ld][k] = sum_dk Wkr[ld][dk] * Wq[k][h*128+dk] -------------
__global__ __launch_bounds__(256) void absorb_q(const u16* __restrict__ Wkr,
                                                const u16* __restrict__ Wqb,
                                                u16* __restrict__ Wq2T) {
  int kb = blockIdx.x, h = blockIdx.y;
  int t = threadIdx.x, w = t >> 6, lane = t & 63, lq = lane & 15, hi = lane >> 4;
  int k0 = kb * 128 + w * 32;
  f32x4 acc[4][2];
#pragma unroll
  for (int i = 0; i < 4; ++i)
#pragma unroll
    for (int j = 0; j < 2; ++j) acc[i][j] = (f32x4){0.f, 0.f, 0.f, 0.f};
#pragma unroll
  for (int kk = 0; kk < 4; ++kk) {
    bf16x8 a[4], bb[2];
#pragma unroll
    for (int fld = 0; fld < 4; ++fld)
      a[fld] = *(const bf16x8*)&Wkr[(fld * 16 + lq) * 128 + kk * 32 + hi * 8];
#pragma unroll
    for (int fk = 0; fk < 2; ++fk)
      bb[fk] = *(const bf16x8*)&Wqb[(size_t)(k0 + fk * 16 + lq) * 2048 + h * 128 + kk * 32 + hi * 8];
#pragma unroll
    for (int fld = 0; fld < 4; ++fld)
#pragma unroll
      for (int fk = 0; fk < 2; ++fk)
        acc[fld][fk] = __builtin_amdgcn_mfma_f32_16x16x32_bf16(a[fld], bb[fk], acc[fld][fk], 0, 0, 0);
  }
#pragma unroll
  for (int fld = 0; fld < 4; ++fld)
#pragma unroll
    for (int fk = 0; fk < 2; ++fk)
#pragma unroll
      for (int r = 0; r < 4; ++r)
        Wq2T[(size_t)(h * 64 + fld * 16 + hi * 4 + r) * 2048 + k0 + fk * 16 + lq] =
            f2bf(acc[fld][fk][r]);
}

// ------------- absorb_o: W2T[n][h*64+ld] = sum_dv WoutT[n][h*128+dv] * Wvr[ld][dv] -------------
__global__ __launch_bounds__(256) void absorb_o(const u16* __restrict__ WoutT,
                                                const u16* __restrict__ Wvr,
                                                u16* __restrict__ W2T) {
  int nb = blockIdx.x, h = blockIdx.y;
  int t = threadIdx.x, w = t >> 6, lane = t & 63, lq = lane & 15, hi = lane >> 4;
  int n0 = nb * 128 + w * 32;
  f32x4 acc[2][4];
#pragma unroll
  for (int i = 0; i < 2; ++i)
#pragma unroll
    for (int j = 0; j < 4; ++j) acc[i][j] = (f32x4){0.f, 0.f, 0.f, 0.f};
#pragma unroll
  for (int kk = 0; kk < 4; ++kk) {
    bf16x8 a[2], bb[4];
#pragma unroll
    for (int fn = 0; fn < 2; ++fn)
      a[fn] = *(const bf16x8*)&WoutT[(size_t)(n0 + fn * 16 + lq) * 2048 + h * 128 + kk * 32 + hi * 8];
#pragma unroll
    for (int fld = 0; fld < 4; ++fld)
      bb[fld] = *(const bf16x8*)&Wvr[(fld * 16 + lq) * 128 + kk * 32 + hi * 8];
#pragma unroll
    for (int fn = 0; fn < 2; ++fn)
#pragma unroll
      for (int fld = 0; fld < 4; ++fld)
        acc[fn][fld] = __builtin_amdgcn_mfma_f32_16x16x32_bf16(a[fn], bb[fld], acc[fn][fld], 0, 0, 0);
  }
#pragma unroll
  for (int fn = 0; fn < 2; ++fn)
#pragma unroll
    for (int fld = 0; fld < 4; ++fld)
#pragma unroll
      for (int r = 0; r < 4; ++r)
        W2T[(size_t)(n0 + fn * 16 + hi * 4 + r) * 1024 + h * 64 + fld * 16 + lq] =
            f2bf(acc[fn][fld][r]);
}

// ------------- absorb_bq: bq2[h*64+ld] = sum_dk bq[h*128+dk]*Wkr[ld][dk] (fp32) -------------
__global__ __launch_bounds__(256) void absorb_bq(const float* __restrict__ bq,
                                                 const float* __restrict__ Wkr,
                                                 float* __restrict__ bq2) {
  int n = blockIdx.x * 256 + threadIdx.x;
  int h = n >> 6, ld = n & 63;
  float s = 0.f;
#pragma unroll 8
  for (int dk = 0; dk < 128; ++dk) s += bq[h * 128 + dk] * Wkr[ld * 128 + dk];
  bq2[n] = s;
}

// ------------- GEMM: C[M,N] = A[M,K](bf16) @ W + bias, W transposed bf16 Wt[N,K] -------------
template <bool OF32>
__global__ __launch_bounds__(256) void gemm_bt_bias(const u16* __restrict__ A,
                                                    const u16* __restrict__ Wt,
                                                    const float* __restrict__ bias,
                                                    void* __restrict__ Cv,
                                                    int M, int N, int K) {
  __shared__ u16 lA[128 * 64];
  __shared__ u16 lB[128 * 64];
  int m0 = blockIdx.y * 128, n0 = blockIdx.x * 128;
  int t = threadIdx.x;
  int lane = t & 63, lq = lane & 15, hi = lane >> 4;
  int w = t >> 6, wm = w >> 1, wn = w & 1;

  f32x4 acc[4][4];
#pragma unroll
  for (int im = 0; im < 4; ++im)
#pragma unroll
    for (int in = 0; in < 4; ++in) acc[im][in] = (f32x4){0.f, 0.f, 0.f, 0.f};

  for (int k0 = 0; k0 < K; k0 += 64) {
    __syncthreads();
#pragma unroll
    for (int i = 0; i < 4; ++i) {
      int idx = i * 256 + t;
      int r = idx >> 3, c8 = (idx & 7) << 3;
      glds16(&Wt[(size_t)(n0 + r) * K + k0 + c8], &lB[idx * 8]);
    }
#pragma unroll
    for (int i = 0; i < 4; ++i) {
      int idx = i * 256 + t;
      int r = idx >> 3, c8 = (idx & 7) << 3;
      glds16(&A[(size_t)(m0 + r) * K + k0 + c8], &lA[idx * 8]);
    }
    __syncthreads();
#pragma unroll
    for (int kk = 0; kk < 2; ++kk) {
      bf16x8 af[4], bfr[4];
#pragma unroll
      for (int im = 0; im < 4; ++im)
        af[im] = *(const bf16x8*)&lA[(wm * 64 + im * 16 + lq) * 64 + kk * 32 + hi * 8];
#pragma unroll
      for (int in = 0; in < 4; ++in)
        bfr[in] = *(const bf16x8*)&lB[(wn * 64 + in * 16 + lq) * 64 + kk * 32 + hi * 8];
#pragma unroll
      for (int im = 0; im < 4; ++im)
#pragma unroll
        for (int in = 0; in < 4; ++in)
          acc[im][in] = __builtin_amdgcn_mfma_f32_16x16x32_bf16(af[im], bfr[in], acc[im][in], 0, 0, 0);
    }
  }
#pragma unroll
  for (int im = 0; im < 4; ++im)
#pragma unroll
    for (int in = 0; in < 4; ++in) {
      int col = n0 + wn * 64 + in * 16 + lq;
      float bv = bias[col];
      int rbase = m0 + wm * 64 + im * 16 + hi * 4;
#pragma unroll
      for (int r = 0; r < 4; ++r) {
        float v = acc[im][in][r] + bv;
        if constexpr (OF32)
          ((float*)Cv)[(size_t)(rbase + r) * N + col] = v;
        else
          ((u16*)Cv)[(size_t)(rbase + r) * N + col] = f2bf(v);
      }
    }
}

// ------------- transpose_lv: LV[b][s][h*64+ld] -> LVt[bh][ld][s], sigma-permuted per 32-s -------------
__global__ __launch_bounds__(256) void transpose_lv(const u16* __restrict__ LV,
                                                    u16* __restrict__ out) {
  __shared__ u16 tile[64 * 72];
  int st = blockIdx.x, bh = blockIdx.y;
  int b = bh >> 4, h = bh & 15;
  int t = threadIdx.x;
  int s0 = st * 64;
#pragma unroll
  for (int i = 0; i < 2; ++i) {
    int idx = i * 256 + t;
    int sr = idx >> 3, c8 = idx & 7;
    bf16x8 v = *(const bf16x8*)&LV[(size_t)(b * S_LEN + s0 + sr) * 1024 + h * 64 + c8 * 8];
    int pos = (sr & 32) + ((sr & 12) << 1) + ((sr & 16) >> 2) + (sr & 3);
#pragma unroll
    for (int j = 0; j < 8; ++j) tile[(c8 * 8 + j) * 72 + pos] = (u16)v[j];
  }
  __syncthreads();
  u16* ob = out + (size_t)bh * 64 * S_LEN;
#pragma unroll
  for (int i = 0; i < 2; ++i) {
    int idx = i * 256 + t;
    int ld = idx >> 3, c8 = idx & 7;
    bf16x8 v = *(const bf16x8*)&tile[ld * 72 + c8 * 8];
    *(bf16x8*)&ob[(size_t)ld * S_LEN + s0 + c8 * 8] = v;
  }
}

// ------------- latent flash attention: head dim 64, 32KB LDS, 512 blocks -------------
__global__ __launch_bounds__(256) void mla_attn4(const u16* __restrict__ Qp,
                                                 const u16* __restrict__ LK,
                                                 const u16* __restrict__ LVt,
                                                 u16* __restrict__ O) {
  __shared__ u16 smem[16384];  // 2buf x (K[64][64] + V[64][64]) = 32KB
  int Lb = blockIdx.x + blockIdx.y * 8;
  int half = Lb >> 8;
  int i0 = Lb & 255;
  int xcd = i0 & 7, ii = i0 >> 3;
  int bh = xcd * 4 + (ii & 3);
  int pr = ii >> 2;
  int qsup = half ? (15 - pr) : pr;
  int b = bh >> 4, h = bh & 15;
  int t = threadIdx.x, w = t >> 6, lane = t & 63, lq = lane & 15, hi = lane >> 4;
  int lq7 = lq & 7;

  const u16* Kb = LK + (size_t)b * S_LEN * 1024 + h * 64;
  const u16* Vb = LVt + (size_t)bh * 64 * S_LEN;
  const float scale = 0.08838834764831845f;  // 1/sqrt(128)  (reference scale)

  auto stage = [&](int buf, int k0) {
    u16* lK = smem + buf * 4096;
    u16* lV = smem + 8192 + buf * 4096;
#pragma unroll
    for (int i = 0; i < 2; ++i) {
      int idx = i * 256 + t;
      int row = idx >> 3, c8 = idx & 7;
      glds16(Kb + (size_t)(k0 + row) * 1024 + ((c8 ^ (row & 7)) << 3), lK + idx * 8);
    }
#pragma unroll
    for (int i = 0; i < 2; ++i) {
      int idx = i * 256 + t;
      int row = idx >> 3, c8 = idx & 7;
      glds16(Vb + (size_t)row * S_LEN + k0 + ((c8 ^ (row & 7)) << 3), lV + idx * 8);
    }
  };

  int qb = qsup * 128;
  int nt = qsup * 2 + 2;
  int kmax = qb + w * 32 + 32;

  bf16x8 qf[2][2];
#pragma unroll
  for (int qi = 0; qi < 2; ++qi) {
    const u16* Qrow = Qp + (size_t)(b * S_LEN + qb + w * 32 + qi * 16 + lq) * 1024 + h * 64;
    qf[qi][0] = *(const bf16x8*)&Qrow[hi * 8];
    qf[qi][1] = *(const bf16x8*)&Qrow[32 + hi * 8];
  }

  f32x4 acc[2][4];
#pragma unroll
  for (int qi = 0; qi < 2; ++qi)
#pragma unroll
    for (int f = 0; f < 4; ++f) acc[qi][f] = (f32x4){0.f, 0.f, 0.f, 0.f};
  float m[2] = {-1e30f, -1e30f}, l[2] = {0.f, 0.f};

  stage(0, 0);
  __syncthreads();
  for (int tt = 0; tt < nt; ++tt) {
    int cur = tt & 1;
    if (tt + 1 < nt) stage(cur ^ 1, (tt + 1) * 64);
    int k0 = tt * 64;
    if (k0 < kmax) {
      const u16* lK = smem + cur * 4096;
      const u16* lV = smem + 8192 + cur * 4096;
      f32x4 sc[2][4];
#pragma unroll
      for (int qi = 0; qi < 2; ++qi)
#pragma unroll
        for (int kf = 0; kf < 4; ++kf) sc[qi][kf] = (f32x4){0.f, 0.f, 0.f, 0.f};
      __builtin_amdgcn_s_setprio(1);
#pragma unroll
      for (int kf = 0; kf < 4; ++kf) {
        const u16* kr = lK + (kf * 16 + lq) * 64;
#pragma unroll
        for (int d0 = 0; d0 < 2; ++d0) {
          bf16x8 af = *(const bf16x8*)&kr[(((d0 << 2) + hi) ^ lq7) << 3];
          sc[0][kf] = __builtin_amdgcn_mfma_f32_16x16x32_bf16(af, qf[0][d0], sc[0][kf], 0, 0, 0);
          sc[1][kf] = __builtin_amdgcn_mfma_f32_16x16x32_bf16(af, qf[1][d0], sc[1][kf], 0, 0, 0);
        }
      }
      __builtin_amdgcn_s_setprio(0);
      bf16x8 pb[2][2];
#pragma unroll
      for (int qi = 0; qi < 2; ++qi) {
        int qfmin = qb + w * 32 + qi * 16;
        int q = qfmin + lq;
        float sv[16];
#pragma unroll
        for (int kf = 0; kf < 4; ++kf)
#pragma unroll
          for (int r = 0; r < 4; ++r) sv[kf * 4 + r] = sc[qi][kf][r] * scale;
        if (k0 + 63 > qfmin) {
#pragma unroll
          for (int kf = 0; kf < 4; ++kf)
#pragma unroll
            for (int r = 0; r < 4; ++r)
              if (k0 + kf * 16 + hi * 4 + r > q) sv[kf * 4 + r] = -1e30f;
        }
        float tm = sv[0];
#pragma unroll
        for (int j = 1; j < 16; ++j) tm = fmaxf(tm, sv[j]);
        tm = fmaxf(tm, __shfl_xor(tm, 16));
        tm = fmaxf(tm, __shfl_xor(tm, 32));
        float p[16], ps = 0.f;
        if (__all(tm <= m[qi] + 8.f)) {
#pragma unroll
          for (int j = 0; j < 16; ++j) { p[j] = __expf(sv[j] - m[qi]); ps += p[j]; }
          ps += __shfl_xor(ps, 16);
          ps += __shfl_xor(ps, 32);
          l[qi] += ps;
        } else {
          float mnew = fmaxf(m[qi], tm);
          float alpha = __expf(m[qi] - mnew);
#pragma unroll
          for (int j = 0; j < 16; ++j) { p[j] = __expf(sv[j] - mnew); ps += p[j]; }
          ps += __shfl_xor(ps, 16);
          ps += __shfl_xor(ps, 32);
          l[qi] = l[qi] * alpha + ps;
          m[qi] = mnew;
#pragma unroll
          for (int f = 0; f < 4; ++f) {
            acc[qi][f][0] *= alpha; acc[qi][f][1] *= alpha;
            acc[qi][f][2] *= alpha; acc[qi][f][3] *= alpha;
          }
        }
#pragma unroll
        for (int ks = 0; ks < 2; ++ks) {
          union { u32x4 u; bf16x8 v; } pu;
#pragma unroll
          for (int wd = 0; wd < 4; ++wd) pu.u[wd] = pk2(p[ks * 8 + 2 * wd], p[ks * 8 + 2 * wd + 1]);
          pb[qi][ks] = pu.v;
        }
      }
      __builtin_amdgcn_s_setprio(1);
#pragma unroll
      for (int f = 0; f < 4; ++f) {
        const u16* vr = lV + (f * 16 + lq) * 64;
#pragma unroll
        for (int ks = 0; ks < 2; ++ks) {
          bf16x8 va = *(const bf16x8*)&vr[(((ks << 2) + hi) ^ lq7) << 3];
          acc[0][f] = __builtin_amdgcn_mfma_f32_16x16x32_bf16(va, pb[0][ks], acc[0][f], 0, 0, 0);
          acc[1][f] = __builtin_amdgcn_mfma_f32_16x16x32_bf16(va, pb[1][ks], acc[1][f], 0, 0, 0);
        }
      }
      __builtin_amdgcn_s_setprio(0);
    }
    __syncthreads();
  }
  // epilogue: swizzled O'^T -> LDS -> coalesced stores (O' is [q][64])
#pragma unroll
  for (int qi = 0; qi < 2; ++qi) {
    float inv = 1.f / l[qi];
    int qloc = w * 32 + qi * 16 + lq;
#pragma unroll
    for (int f = 0; f < 4; ++f)
#pragma unroll
      for (int r = 0; r < 4; ++r) {
        int col = f * 16 + hi * 4 + r;
        smem[qloc * 64 + (((col >> 3) ^ lq7) << 3) + (col & 7)] = f2bf(acc[qi][f][r] * inv);
      }
  }
  __syncthreads();
#pragma unroll
  for (int i = 0; i < 4; ++i) {
    int cid = i * 256 + t;
    int q = cid >> 3, ch = cid & 7;
    bf16x8 v = *(const bf16x8*)&smem[q * 64 + ((ch ^ (q & 7)) << 3)];
    *(bf16x8*)&O[(size_t)(b * S_LEN + qb + q) * 1024 + h * 64 + (ch << 3)] = v;
  }
}

extern "C" void kernel_launch(void* const* d_in, const int* in_sizes, int n_in,
                              void* d_out, int out_size, void* d_ws, size_t ws_size,
                              hipStream_t stream) {
  const float* queries = (const float*)d_in[0];
  const float* keys    = (const float*)d_in[1];
  const float* values  = (const float*)d_in[2];
  const float* Wq      = (const float*)d_in[3];
  const float* bq      = (const float*)d_in[4];
  const float* Wlk     = (const float*)d_in[5];
  const float* blk     = (const float*)d_in[6];
  const float* Wlv     = (const float*)d_in[7];
  const float* blv     = (const float*)d_in[8];
  const float* Wkr     = (const float*)d_in[9];
  const float* Wvr     = (const float*)d_in[10];
  const float* Wout    = (const float*)d_in[11];
  const float* bout    = (const float*)d_in[12];

  u16* ws = (u16*)d_ws;
  u16* WqBf  = ws; ws += (size_t)2048 * 2048;   // Wq bf16 row-major
  u16* WkrBf = ws; ws += 64 * 128;
  u16* WvrBf = ws; ws += 64 * 128;
  u16* WoutT = ws; ws += (size_t)2048 * 2048;
  u16* WlkT  = ws; ws += (size_t)1024 * 2048;
  u16* WlvT  = ws; ws += (size_t)1024 * 2048;
  u16* Wq2T  = ws; ws += (size_t)1024 * 2048;
  u16* W2T   = ws; ws += (size_t)2048 * 1024;
  float* bq2 = (float*)ws; ws += 2048;          // 1024 floats
  u16* Qin   = ws; ws += (size_t)4096 * 2048;
  u16* Kin   = ws; ws += (size_t)4096 * 2048;
  u16* Vin   = ws; ws += (size_t)4096 * 2048;
  u16* Qp    = ws; ws += (size_t)4096 * 1024;
  u16* LKb   = ws; ws += (size_t)4096 * 1024;
  u16* LVb   = ws; ws += (size_t)4096 * 1024;
  // aliases (strict same-stream ordering): LVt after lk-GEMM consumed Kin; Ob after q'-GEMM consumed Qin
  u16* LVt = Kin;
  u16* Ob  = Qin;

  dim3 blk256(256);
  cast_f32_bf16<<<dim3(4096), blk256, 0, stream>>>(queries, Qin);
  cast_f32_bf16<<<dim3(4096), blk256, 0, stream>>>(keys, Kin);
  cast_f32_bf16<<<dim3(4096), blk256, 0, stream>>>(values, Vin);
  cast_f32_bf16<<<dim3(2048), blk256, 0, stream>>>(Wq, WqBf);
  cast_f32_bf16<<<dim3(4), blk256, 0, stream>>>(Wkr, WkrBf);
  cast_f32_bf16<<<dim3(4), blk256, 0, stream>>>(Wvr, WvrBf);

  transpose_f32_bf16<<<dim3(16, 32), blk256, 0, stream>>>(Wlk, WlkT, 2048, 1024);
  transpose_f32_bf16<<<dim3(16, 32), blk256, 0, stream>>>(Wlv, WlvT, 2048, 1024);
  transpose_f32_bf16<<<dim3(32, 32), blk256, 0, stream>>>(Wout, WoutT, 2048, 2048);

  absorb_q<<<dim3(16, 16), blk256, 0, stream>>>(WkrBf, WqBf, Wq2T);
  absorb_o<<<dim3(16, 16), blk256, 0, stream>>>(WoutT, WvrBf, W2T);
  absorb_bq<<<dim3(4), blk256, 0, stream>>>(bq, Wkr, bq2);

  gemm_bt_bias<false><<<dim3(8, 32), blk256, 0, stream>>>(Qin, Wq2T, bq2, Qp, 4096, 1024, 2048);
  gemm_bt_bias<false><<<dim3(8, 32), blk256, 0, stream>>>(Kin, WlkT, blk, LKb, 4096, 1024, 2048);
  gemm_bt_bias<false><<<dim3(8, 32), blk256, 0, stream>>>(Vin, WlvT, blv, LVb, 4096, 1024, 2048);

  transpose_lv<<<dim3(32, 32), blk256, 0, stream>>>(LVb, LVt);

  mla_attn4<<<dim3(8, 64), blk256, 0, stream>>>(Qp, LKb, LVt, Ob);

  gemm_bt_bias<true><<<dim3(16, 32), blk256, 0, stream>>>(Ob, W2T, bout, (float*)d_out, 4096, 2048, 1024);
}

// Round 6
// 230.180 us; speedup vs baseline: 4.2100x; 1.3017x over previous
//
#include <hip/hip_runtime.h>

#define S_LEN 2048
#define NH 16

typedef unsigned short u16;
typedef __attribute__((ext_vector_type(8))) short bf16x8;
typedef __attribute__((ext_vector_type(4))) short s16x4;
typedef __attribute__((ext_vector_type(4))) unsigned short u16x4;
typedef __attribute__((ext_vector_type(4))) unsigned int u32x4;
typedef __attribute__((ext_vector_type(4))) float f32x4;

__device__ __forceinline__ u16 f2bf(float f) {
  union { float f; unsigned int i; } x; x.f = f;
  unsigned int r = x.i + 0x7FFFu + ((x.i >> 16) & 1u);
  return (u16)(r >> 16);
}
__device__ __forceinline__ unsigned pk2(float lo, float hi) {
  unsigned r;
  asm("v_cvt_pk_bf16_f32 %0, %1, %2" : "=v"(r) : "v"(lo), "v"(hi));
  return r;
}
__device__ __forceinline__ void glds16(const void* g, void* l) {
  __builtin_amdgcn_global_load_lds((const __attribute__((address_space(1))) void*)g,
                                   (__attribute__((address_space(3))) void*)l, 16, 0, 0);
}

// ---------------- cast fp32 -> bf16: 3 tensors in one dispatch (blockIdx.y selects) ----------------
__global__ __launch_bounds__(256) void cast3_f32_bf16(const float* __restrict__ i0,
                                                      const float* __restrict__ i1,
                                                      const float* __restrict__ i2,
                                                      u16* __restrict__ o0,
                                                      u16* __restrict__ o1,
                                                      u16* __restrict__ o2) {
  int z = blockIdx.y;
  const float* in = z == 0 ? i0 : (z == 1 ? i1 : i2);
  u16* out = z == 0 ? o0 : (z == 1 ? o1 : o2);
  size_t i = ((size_t)blockIdx.x * 256 + threadIdx.x) * 8;
  f32x4 a = *(const f32x4*)&in[i];
  f32x4 b = *(const f32x4*)&in[i + 4];
  u32x4 o;
  o[0] = pk2(a[0], a[1]);
  o[1] = pk2(a[2], a[3]);
  o[2] = pk2(b[0], b[1]);
  o[3] = pk2(b[2], b[3]);
  *(u32x4*)&out[i] = o;
}

__global__ __launch_bounds__(256) void cast_f32_bf16(const float* __restrict__ in,
                                                     u16* __restrict__ out) {
  size_t i = ((size_t)blockIdx.x * 256 + threadIdx.x) * 8;
  f32x4 a = *(const f32x4*)&in[i];
  f32x4 b = *(const f32x4*)&in[i + 4];
  u32x4 o;
  o[0] = pk2(a[0], a[1]);
  o[1] = pk2(a[2], a[3]);
  o[2] = pk2(b[0], b[1]);
  o[3] = pk2(b[2], b[3]);
  *(u32x4*)&out[i] = o;
}

__global__ __launch_bounds__(256) void cast2_f32_bf16(const float* __restrict__ i0,
                                                      const float* __restrict__ i1,
                                                      u16* __restrict__ o0,
                                                      u16* __restrict__ o1) {
  const float* in = blockIdx.y ? i1 : i0;
  u16* out = blockIdx.y ? o1 : o0;
  size_t i = ((size_t)blockIdx.x * 256 + threadIdx.x) * 8;
  f32x4 a = *(const f32x4*)&in[i];
  f32x4 b = *(const f32x4*)&in[i + 4];
  u32x4 o;
  o[0] = pk2(a[0], a[1]);
  o[1] = pk2(a[2], a[3]);
  o[2] = pk2(b[0], b[1]);
  o[3] = pk2(b[2], b[3]);
  *(u32x4*)&out[i] = o;
}

// ---------------- transpose+cast: in [K,N] fp32 -> out [N,K] bf16 (z selects tensor pair) ----------------
__global__ __launch_bounds__(256) void transpose2_f32_bf16(const float* __restrict__ i0,
                                                           const float* __restrict__ i1,
                                                           u16* __restrict__ o0,
                                                           u16* __restrict__ o1,
                                                           int K, int N) {
  const float* in = blockIdx.z ? i1 : i0;
  u16* out = blockIdx.z ? o1 : o0;
  __shared__ u16 tile[64][72];
  int k0 = blockIdx.y * 64, n0 = blockIdx.x * 64;
  int t = threadIdx.x;
#pragma unroll
  for (int i = 0; i < 4; ++i) {
    int idx = i * 256 + t;
    int r = idx >> 4;
    int c4 = (idx & 15) << 2;
    f32x4 v = *(const f32x4*)&in[(size_t)(k0 + r) * N + n0 + c4];
#pragma unroll
    for (int j = 0; j < 4; ++j) tile[r][c4 + j] = f2bf(v[j]);
  }
  __syncthreads();
#pragma unroll
  for (int i = 0; i < 4; ++i) {
    int idx = i * 256 + t;
    int r = idx >> 4;
    int c4 = (idx & 15) << 2;
    u16x4 v;
    v[0] = tile[c4 + 0][r];
    v[1] = tile[c4 + 1][r];
    v[2] = tile[c4 + 2][r];
    v[3] = tile[c4 + 3][r];
    *(u16x4*)&out[(size_t)(n0 + r) * K + k0 + c4] = v;
  }
}

__global__ __launch_bounds__(256) void transpose_f32_bf16(const float* __restrict__ in,
                                                          u16* __restrict__ out,
                                                          int K, int N) {
  __shared__ u16 tile[64][72];
  int k0 = blockIdx.y * 64, n0 = blockIdx.x * 64;
  int t = threadIdx.x;
#pragma unroll
  for (int i = 0; i < 4; ++i) {
    int idx = i * 256 + t;
    int r = idx >> 4;
    int c4 = (idx & 15) << 2;
    f32x4 v = *(const f32x4*)&in[(size_t)(k0 + r) * N + n0 + c4];
#pragma unroll
    for (int j = 0; j < 4; ++j) tile[r][c4 + j] = f2bf(v[j]);
  }
  __syncthreads();
#pragma unroll
  for (int i = 0; i < 4; ++i) {
    int idx = i * 256 + t;
    int r = idx >> 4;
    int c4 = (idx & 15) << 2;
    u16x4 v;
    v[0] = tile[c4 + 0][r];
    v[1] = tile[c4 + 1][r];
    v[2] = tile[c4 + 2][r];
    v[3] = tile[c4 + 3][r];
    *(u16x4*)&out[(size_t)(n0 + r) * K + k0 + c4] = v;
  }
}

// ------------- absorb_q: Wq2T[h*64+ld][k] = sum_dk Wkr[ld][dk] * Wq[k][h*128+dk] -------------
__global__ __launch_bounds__(256) void absorb_q(const u16* __restrict__ Wkr,
                                                const u16* __restrict__ Wqb,
                                                u16* __restrict__ Wq2T) {
  int kb = blockIdx.x, h = blockIdx.y;
  int t = threadIdx.x, w = t >> 6, lane = t & 63, lq = lane & 15, hi = lane >> 4;
  int k0 = kb * 128 + w * 32;
  f32x4 acc[4][2];
#pragma unroll
  for (int i = 0; i < 4; ++i)
#pragma unroll
    for (int j = 0; j < 2; ++j) acc[i][j] = (f32x4){0.f, 0.f, 0.f, 0.f};
#pragma unroll
  for (int kk = 0; kk < 4; ++kk) {
    bf16x8 a[4], bb[2];
#pragma unroll
    for (int fld = 0; fld < 4; ++fld)
      a[fld] = *(const bf16x8*)&Wkr[(fld * 16 + lq) * 128 + kk * 32 + hi * 8];
#pragma unroll
    for (int fk = 0; fk < 2; ++fk)
      bb[fk] = *(const bf16x8*)&Wqb[(size_t)(k0 + fk * 16 + lq) * 2048 + h * 128 + kk * 32 + hi * 8];
#pragma unroll
    for (int fld = 0; fld < 4; ++fld)
#pragma unroll
      for (int fk = 0; fk < 2; ++fk)
        acc[fld][fk] = __builtin_amdgcn_mfma_f32_16x16x32_bf16(a[fld], bb[fk], acc[fld][fk], 0, 0, 0);
  }
#pragma unroll
  for (int fld = 0; fld < 4; ++fld)
#pragma unroll
    for (int fk = 0; fk < 2; ++fk)
#pragma unroll
      for (int r = 0; r < 4; ++r)
        Wq2T[(size_t)(h * 64 + fld * 16 + hi * 4 + r) * 2048 + k0 + fk * 16 + lq] =
            f2bf(acc[fld][fk][r]);
}

// ------------- absorb_o: W2T[n][h*64+ld] = sum_dv WoutT[n][h*128+dv] * Wvr[ld][dv] -------------
__global__ __launch_bounds__(256) void absorb_o(const u16* __restrict__ WoutT,
                                                const u16* __restrict__ Wvr,
                                                u16* __restrict__ W2T) {
  int nb = blockIdx.x, h = blockIdx.y;
  int t = threadIdx.x, w = t >> 6, lane = t & 63, lq = lane & 15, hi = lane >> 4;
  int n0 = nb * 128 + w * 32;
  f32x4 acc[2][4];
#pragma unroll
  for (int i = 0; i < 2; ++i)
#pragma unroll
    for (int j = 0; j < 4; ++j) acc[i][j] = (f32x4){0.f, 0.f, 0.f, 0.f};
#pragma unroll
  for (int kk = 0; kk < 4; ++kk) {
    bf16x8 a[2], bb[4];
#pragma unroll
    for (int fn = 0; fn < 2; ++fn)
      a[fn] = *(const bf16x8*)&WoutT[(size_t)(n0 + fn * 16 + lq) * 2048 + h * 128 + kk * 32 + hi * 8];
#pragma unroll
    for (int fld = 0; fld < 4; ++fld)
      bb[fld] = *(const bf16x8*)&Wvr[(fld * 16 + lq) * 128 + kk * 32 + hi * 8];
#pragma unroll
    for (int fn = 0; fn < 2; ++fn)
#pragma unroll
      for (int fld = 0; fld < 4; ++fld)
        acc[fn][fld] = __builtin_amdgcn_mfma_f32_16x16x32_bf16(a[fn], bb[fld], acc[fn][fld], 0, 0, 0);
  }
#pragma unroll
  for (int fn = 0; fn < 2; ++fn)
#pragma unroll
    for (int fld = 0; fld < 4; ++fld)
#pragma unroll
      for (int r = 0; r < 4; ++r)
        W2T[(size_t)(n0 + fn * 16 + hi * 4 + r) * 1024 + h * 64 + fld * 16 + lq] =
            f2bf(acc[fn][fld][r]);
}

// ------------- absorb_bq: bq2[h*64+ld] = sum_dk bq[h*128+dk]*Wkr[ld][dk] (fp32) -------------
__global__ __launch_bounds__(256) void absorb_bq(const float* __restrict__ bq,
                                                 const float* __restrict__ Wkr,
                                                 float* __restrict__ bq2) {
  int n = blockIdx.x * 256 + threadIdx.x;
  int h = n >> 6, ld = n & 63;
  float s = 0.f;
#pragma unroll 8
  for (int dk = 0; dk < 128; ++dk) s += bq[h * 128 + dk] * Wkr[ld * 128 + dk];
  bq2[n] = s;
}

// ------------- GEMM body (128x128 tile, BK=64, global_load_lds) -------------
template <bool OF32>
__device__ __forceinline__ void gemm_body(const u16* __restrict__ A,
                                          const u16* __restrict__ Wt,
                                          const float* __restrict__ bias,
                                          void* __restrict__ Cv,
                                          int M, int N, int K,
                                          u16* lA, u16* lB) {
  int m0 = blockIdx.y * 128, n0 = blockIdx.x * 128;
  int t = threadIdx.x;
  int lane = t & 63, lq = lane & 15, hi = lane >> 4;
  int w = t >> 6, wm = w >> 1, wn = w & 1;

  f32x4 acc[4][4];
#pragma unroll
  for (int im = 0; im < 4; ++im)
#pragma unroll
    for (int in = 0; in < 4; ++in) acc[im][in] = (f32x4){0.f, 0.f, 0.f, 0.f};

  for (int k0 = 0; k0 < K; k0 += 64) {
    __syncthreads();
#pragma unroll
    for (int i = 0; i < 4; ++i) {
      int idx = i * 256 + t;
      int r = idx >> 3, c8 = (idx & 7) << 3;
      glds16(&Wt[(size_t)(n0 + r) * K + k0 + c8], &lB[idx * 8]);
    }
#pragma unroll
    for (int i = 0; i < 4; ++i) {
      int idx = i * 256 + t;
      int r = idx >> 3, c8 = (idx & 7) << 3;
      glds16(&A[(size_t)(m0 + r) * K + k0 + c8], &lA[idx * 8]);
    }
    __syncthreads();
#pragma unroll
    for (int kk = 0; kk < 2; ++kk) {
      bf16x8 af[4], bfr[4];
#pragma unroll
      for (int im = 0; im < 4; ++im)
        af[im] = *(const bf16x8*)&lA[(wm * 64 + im * 16 + lq) * 64 + kk * 32 + hi * 8];
#pragma unroll
      for (int in = 0; in < 4; ++in)
        bfr[in] = *(const bf16x8*)&lB[(wn * 64 + in * 16 + lq) * 64 + kk * 32 + hi * 8];
#pragma unroll
      for (int im = 0; im < 4; ++im)
#pragma unroll
        for (int in = 0; in < 4; ++in)
          acc[im][in] = __builtin_amdgcn_mfma_f32_16x16x32_bf16(af[im], bfr[in], acc[im][in], 0, 0, 0);
    }
  }
#pragma unroll
  for (int im = 0; im < 4; ++im)
#pragma unroll
    for (int in = 0; in < 4; ++in) {
      int col = n0 + wn * 64 + in * 16 + lq;
      float bv = bias[col];
      int rbase = m0 + wm * 64 + im * 16 + hi * 4;
#pragma unroll
      for (int r = 0; r < 4; ++r) {
        float v = acc[im][in][r] + bv;
        if constexpr (OF32)
          ((float*)Cv)[(size_t)(rbase + r) * N + col] = v;
        else
          ((u16*)Cv)[(size_t)(rbase + r) * N + col] = f2bf(v);
      }
    }
}

template <bool OF32>
__global__ __launch_bounds__(256) void gemm_bt_bias(const u16* __restrict__ A,
                                                    const u16* __restrict__ Wt,
                                                    const float* __restrict__ bias,
                                                    void* __restrict__ Cv,
                                                    int M, int N, int K) {
  __shared__ u16 lA[128 * 64];
  __shared__ u16 lB[128 * 64];
  gemm_body<OF32>(A, Wt, bias, Cv, M, N, K, lA, lB);
}

// ------------- fused 3-projection GEMM: z selects {Q', LK, LV}; all M4096 N1024 K2048 -------------
__global__ __launch_bounds__(256) void gemm3_proj(const u16* __restrict__ A0,
                                                  const u16* __restrict__ A1,
                                                  const u16* __restrict__ A2,
                                                  const u16* __restrict__ W0,
                                                  const u16* __restrict__ W1,
                                                  const u16* __restrict__ W2,
                                                  const float* __restrict__ b0,
                                                  const float* __restrict__ b1,
                                                  const float* __restrict__ b2,
                                                  u16* __restrict__ C0,
                                                  u16* __restrict__ C1,
                                                  u16* __restrict__ C2) {
  __shared__ u16 lA[128 * 64];
  __shared__ u16 lB[128 * 64];
  int z = blockIdx.z;
  const u16* A = z == 0 ? A0 : (z == 1 ? A1 : A2);
  const u16* Wt = z == 0 ? W0 : (z == 1 ? W1 : W2);
  const float* bias = z == 0 ? b0 : (z == 1 ? b1 : b2);
  u16* C = z == 0 ? C0 : (z == 1 ? C1 : C2);
  gemm_body<false>(A, Wt, bias, C, 4096, 1024, 2048, lA, lB);
}

// ------------- transpose_lv: LV[b][s][h*64+ld] -> LVt[bh][ld][s], sigma-permuted per 32-s -------------
__global__ __launch_bounds__(256) void transpose_lv(const u16* __restrict__ LV,
                                                    u16* __restrict__ out) {
  __shared__ u16 tile[64 * 72];
  int st = blockIdx.x, bh = blockIdx.y;
  int b = bh >> 4, h = bh & 15;
  int t = threadIdx.x;
  int s0 = st * 64;
#pragma unroll
  for (int i = 0; i < 2; ++i) {
    int idx = i * 256 + t;
    int sr = idx >> 3, c8 = idx & 7;
    bf16x8 v = *(const bf16x8*)&LV[(size_t)(b * S_LEN + s0 + sr) * 1024 + h * 64 + c8 * 8];
    int pos = (sr & 32) + ((sr & 12) << 1) + ((sr & 16) >> 2) + (sr & 3);
#pragma unroll
    for (int j = 0; j < 8; ++j) tile[(c8 * 8 + j) * 72 + pos] = (u16)v[j];
  }
  __syncthreads();
  u16* ob = out + (size_t)bh * 64 * S_LEN;
#pragma unroll
  for (int i = 0; i < 2; ++i) {
    int idx = i * 256 + t;
    int ld = idx >> 3, c8 = idx & 7;
    bf16x8 v = *(const bf16x8*)&tile[ld * 72 + c8 * 8];
    *(bf16x8*)&ob[(size_t)ld * S_LEN + s0 + c8 * 8] = v;
  }
}

// ------------- latent flash attention: QBLK=64, 1024 blocks (4/CU), 32KB LDS -------------
__global__ __launch_bounds__(256) void mla_attn5(const u16* __restrict__ Qp,
                                                 const u16* __restrict__ LK,
                                                 const u16* __restrict__ LVt,
                                                 u16* __restrict__ O) {
  __shared__ u16 smem[16384];  // 2buf x (K[64][64] + V[64][64]) = 32KB
  int Lb = blockIdx.x + blockIdx.y * 8;
  int half = Lb >> 9;
  int i0 = Lb & 511;
  int xcd = i0 & 7, ii = i0 >> 3;
  int bh = xcd * 4 + (ii & 3);
  int pr = ii >> 2;                 // 0..15
  int qsup = half ? (31 - pr) : pr; // pairs sum to 33 tiles
  int b = bh >> 4, h = bh & 15;
  int t = threadIdx.x, w = t >> 6, lane = t & 63, lq = lane & 15, hi = lane >> 4;
  int lq7 = lq & 7;

  const u16* Kb = LK + (size_t)b * S_LEN * 1024 + h * 64;
  const u16* Vb = LVt + (size_t)bh * 64 * S_LEN;
  const float scale = 0.08838834764831845f;  // 1/sqrt(128)

  auto stage = [&](int buf, int k0) {
    u16* lK = smem + buf * 4096;
    u16* lV = smem + 8192 + buf * 4096;
#pragma unroll
    for (int i = 0; i < 2; ++i) {
      int idx = i * 256 + t;
      int row = idx >> 3, c8 = idx & 7;
      glds16(Kb + (size_t)(k0 + row) * 1024 + ((c8 ^ (row & 7)) << 3), lK + idx * 8);
    }
#pragma unroll
    for (int i = 0; i < 2; ++i) {
      int idx = i * 256 + t;
      int row = idx >> 3, c8 = idx & 7;
      glds16(Vb + (size_t)row * S_LEN + k0 + ((c8 ^ (row & 7)) << 3), lV + idx * 8);
    }
  };

  int qb = qsup * 64;
  int nt = qsup + 1;
  int q0 = qb + w * 16;   // this wave's 16 q-rows
  int kmax = q0 + 16;

  bf16x8 qf[2];
  {
    const u16* Qrow = Qp + (size_t)(b * S_LEN + q0 + lq) * 1024 + h * 64;
    qf[0] = *(const bf16x8*)&Qrow[hi * 8];
    qf[1] = *(const bf16x8*)&Qrow[32 + hi * 8];
  }

  f32x4 acc[4];
#pragma unroll
  for (int f = 0; f < 4; ++f) acc[f] = (f32x4){0.f, 0.f, 0.f, 0.f};
  float m = -1e30f, l = 0.f;

  stage(0, 0);
  __syncthreads();
  for (int tt = 0; tt < nt; ++tt) {
    int cur = tt & 1;
    if (tt + 1 < nt) stage(cur ^ 1, (tt + 1) * 64);
    int k0 = tt * 64;
    if (k0 < kmax) {
      const u16* lK = smem + cur * 4096;
      const u16* lV = smem + 8192 + cur * 4096;
      f32x4 sc[4];
#pragma unroll
      for (int kf = 0; kf < 4; ++kf) sc[kf] = (f32x4){0.f, 0.f, 0.f, 0.f};
      __builtin_amdgcn_s_setprio(1);
#pragma unroll
      for (int kf = 0; kf < 4; ++kf) {
        const u16* kr = lK + (kf * 16 + lq) * 64;
#pragma unroll
        for (int d0 = 0; d0 < 2; ++d0) {
          bf16x8 af = *(const bf16x8*)&kr[(((d0 << 2) + hi) ^ lq7) << 3];
          sc[kf] = __builtin_amdgcn_mfma_f32_16x16x32_bf16(af, qf[d0], sc[kf], 0, 0, 0);
        }
      }
      __builtin_amdgcn_s_setprio(0);
      int q = q0 + lq;
      float sv[16];
#pragma unroll
      for (int kf = 0; kf < 4; ++kf)
#pragma unroll
        for (int r = 0; r < 4; ++r) sv[kf * 4 + r] = sc[kf][r] * scale;
      if (k0 + 63 > q0) {
#pragma unroll
        for (int kf = 0; kf < 4; ++kf)
#pragma unroll
          for (int r = 0; r < 4; ++r)
            if (k0 + kf * 16 + hi * 4 + r > q) sv[kf * 4 + r] = -1e30f;
      }
      float tm = sv[0];
#pragma unroll
      for (int j = 1; j < 16; ++j) tm = fmaxf(tm, sv[j]);
      tm = fmaxf(tm, __shfl_xor(tm, 16));
      tm = fmaxf(tm, __shfl_xor(tm, 32));
      float p[16], ps = 0.f;
      if (__all(tm <= m + 8.f)) {
#pragma unroll
        for (int j = 0; j < 16; ++j) { p[j] = __expf(sv[j] - m); ps += p[j]; }
        ps += __shfl_xor(ps, 16);
        ps += __shfl_xor(ps, 32);
        l += ps;
      } else {
        float mnew = fmaxf(m, tm);
        float alpha = __expf(m - mnew);
#pragma unroll
        for (int j = 0; j < 16; ++j) { p[j] = __expf(sv[j] - mnew); ps += p[j]; }
        ps += __shfl_xor(ps, 16);
        ps += __shfl_xor(ps, 32);
        l = l * alpha + ps;
        m = mnew;
#pragma unroll
        for (int f = 0; f < 4; ++f) {
          acc[f][0] *= alpha; acc[f][1] *= alpha;
          acc[f][2] *= alpha; acc[f][3] *= alpha;
        }
      }
      bf16x8 pb[2];
#pragma unroll
      for (int ks = 0; ks < 2; ++ks) {
        union { u32x4 u; bf16x8 v; } pu;
#pragma unroll
        for (int wd = 0; wd < 4; ++wd) pu.u[wd] = pk2(p[ks * 8 + 2 * wd], p[ks * 8 + 2 * wd + 1]);
        pb[ks] = pu.v;
      }
      __builtin_amdgcn_s_setprio(1);
#pragma unroll
      for (int f = 0; f < 4; ++f) {
        const u16* vr = lV + (f * 16 + lq) * 64;
#pragma unroll
        for (int ks = 0; ks < 2; ++ks) {
          bf16x8 va = *(const bf16x8*)&vr[(((ks << 2) + hi) ^ lq7) << 3];
          acc[f] = __builtin_amdgcn_mfma_f32_16x16x32_bf16(va, pb[ks], acc[f], 0, 0, 0);
        }
      }
      __builtin_amdgcn_s_setprio(0);
    }
    __syncthreads();
  }
  // epilogue: swizzled O'^T -> LDS -> coalesced stores (O' is [64 q][64 dv])
  {
    float inv = 1.f / l;
    int qloc = w * 16 + lq;
#pragma unroll
    for (int f = 0; f < 4; ++f)
#pragma unroll
      for (int r = 0; r < 4; ++r) {
        int col = f * 16 + hi * 4 + r;
        smem[qloc * 64 + (((col >> 3) ^ lq7) << 3) + (col & 7)] = f2bf(acc[f][r] * inv);
      }
  }
  __syncthreads();
#pragma unroll
  for (int i = 0; i < 2; ++i) {
    int cid = i * 256 + t;
    int q = cid >> 3, ch = cid & 7;
    bf16x8 v = *(const bf16x8*)&smem[q * 64 + ((ch ^ (q & 7)) << 3)];
    *(bf16x8*)&O[(size_t)(b * S_LEN + qb + q) * 1024 + h * 64 + (ch << 3)] = v;
  }
}

extern "C" void kernel_launch(void* const* d_in, const int* in_sizes, int n_in,
                              void* d_out, int out_size, void* d_ws, size_t ws_size,
                              hipStream_t stream) {
  const float* queries = (const float*)d_in[0];
  const float* keys    = (const float*)d_in[1];
  const float* values  = (const float*)d_in[2];
  const float* Wq      = (const float*)d_in[3];
  const float* bq      = (const float*)d_in[4];
  const float* Wlk     = (const float*)d_in[5];
  const float* blk     = (const float*)d_in[6];
  const float* Wlv     = (const float*)d_in[7];
  const float* blv     = (const float*)d_in[8];
  const float* Wkr     = (const float*)d_in[9];
  const float* Wvr     = (const float*)d_in[10];
  const float* Wout    = (const float*)d_in[11];
  const float* bout    = (const float*)d_in[12];

  u16* ws = (u16*)d_ws;
  u16* WqBf  = ws; ws += (size_t)2048 * 2048;
  u16* WkrBf = ws; ws += 64 * 128;
  u16* WvrBf = ws; ws += 64 * 128;
  u16* WoutT = ws; ws += (size_t)2048 * 2048;
  u16* WlkT  = ws; ws += (size_t)1024 * 2048;
  u16* WlvT  = ws; ws += (size_t)1024 * 2048;
  u16* Wq2T  = ws; ws += (size_t)1024 * 2048;
  u16* W2T   = ws; ws += (size_t)2048 * 1024;
  float* bq2 = (float*)ws; ws += 2048;
  u16* Qin   = ws; ws += (size_t)4096 * 2048;
  u16* Kin   = ws; ws += (size_t)4096 * 2048;
  u16* Vin   = ws; ws += (size_t)4096 * 2048;
  u16* Qp    = ws; ws += (size_t)4096 * 1024;
  u16* LKb   = ws; ws += (size_t)4096 * 1024;
  u16* LVb   = ws; ws += (size_t)4096 * 1024;
  u16* LVt = Kin;  // alias: written after gemm3_proj consumed Kin
  u16* Ob  = Qin;  // alias: written after gemm3_proj consumed Qin

  dim3 blk256(256);
  cast3_f32_bf16<<<dim3(4096, 3), blk256, 0, stream>>>(queries, keys, values, Qin, Kin, Vin);
  cast_f32_bf16<<<dim3(2048), blk256, 0, stream>>>(Wq, WqBf);
  cast2_f32_bf16<<<dim3(4, 2), blk256, 0, stream>>>(Wkr, Wvr, WkrBf, WvrBf);

  transpose2_f32_bf16<<<dim3(16, 32, 2), blk256, 0, stream>>>(Wlk, Wlv, WlkT, WlvT, 2048, 1024);
  transpose_f32_bf16<<<dim3(32, 32), blk256, 0, stream>>>(Wout, WoutT, 2048, 2048);

  absorb_q<<<dim3(16, 16), blk256, 0, stream>>>(WkrBf, WqBf, Wq2T);
  absorb_o<<<dim3(16, 16), blk256, 0, stream>>>(WoutT, WvrBf, W2T);
  absorb_bq<<<dim3(4), blk256, 0, stream>>>(bq, Wkr, bq2);

  gemm3_proj<<<dim3(8, 32, 3), blk256, 0, stream>>>(Qin, Kin, Vin,
                                                    Wq2T, WlkT, WlvT,
                                                    bq2, blk, blv,
                                                    Qp, LKb, LVb);

  transpose_lv<<<dim3(32, 32), blk256, 0, stream>>>(LVb, LVt);

  mla_attn5<<<dim3(8, 128), blk256, 0, stream>>>(Qp, LKb, LVt, Ob);

  gemm_bt_bias<true><<<dim3(16, 32), blk256, 0, stream>>>(Ob, W2T, bout, (float*)d_out, 4096, 2048, 1024);
}

// Round 7
// 211.164 us; speedup vs baseline: 4.5891x; 1.0901x over previous
//
#include <hip/hip_runtime.h>

#define S_LEN 2048
#define NH 16

typedef unsigned short u16;
typedef __attribute__((ext_vector_type(8))) short bf16x8;
typedef __attribute__((ext_vector_type(4))) short s16x4;
typedef __attribute__((ext_vector_type(4))) unsigned short u16x4;
typedef __attribute__((ext_vector_type(4))) unsigned int u32x4;
typedef __attribute__((ext_vector_type(4))) float f32x4;

__device__ __forceinline__ u16 f2bf(float f) {
  union { float f; unsigned int i; } x; x.f = f;
  unsigned int r = x.i + 0x7FFFu + ((x.i >> 16) & 1u);
  return (u16)(r >> 16);
}
__device__ __forceinline__ unsigned pk2(float lo, float hi) {
  unsigned r;
  asm("v_cvt_pk_bf16_f32 %0, %1, %2" : "=v"(r) : "v"(lo), "v"(hi));
  return r;
}
__device__ __forceinline__ void glds16(const void* g, void* l) {
  __builtin_amdgcn_global_load_lds((const __attribute__((address_space(1))) void*)g,
                                   (__attribute__((address_space(3))) void*)l, 16, 0, 0);
}

// ---------------- cast fp32 -> bf16: 3 tensors (blockIdx.y selects) ----------------
__global__ __launch_bounds__(256) void cast3_f32_bf16(const float* __restrict__ i0,
                                                      const float* __restrict__ i1,
                                                      const float* __restrict__ i2,
                                                      u16* __restrict__ o0,
                                                      u16* __restrict__ o1,
                                                      u16* __restrict__ o2) {
  int z = blockIdx.y;
  const float* in = z == 0 ? i0 : (z == 1 ? i1 : i2);
  u16* out = z == 0 ? o0 : (z == 1 ? o1 : o2);
  size_t i = ((size_t)blockIdx.x * 256 + threadIdx.x) * 8;
  f32x4 a = *(const f32x4*)&in[i];
  f32x4 b = *(const f32x4*)&in[i + 4];
  u32x4 o;
  o[0] = pk2(a[0], a[1]);
  o[1] = pk2(a[2], a[3]);
  o[2] = pk2(b[0], b[1]);
  o[3] = pk2(b[2], b[3]);
  *(u32x4*)&out[i] = o;
}

__global__ __launch_bounds__(256) void cast_f32_bf16(const float* __restrict__ in,
                                                     u16* __restrict__ out) {
  size_t i = ((size_t)blockIdx.x * 256 + threadIdx.x) * 8;
  f32x4 a = *(const f32x4*)&in[i];
  f32x4 b = *(const f32x4*)&in[i + 4];
  u32x4 o;
  o[0] = pk2(a[0], a[1]);
  o[1] = pk2(a[2], a[3]);
  o[2] = pk2(b[0], b[1]);
  o[3] = pk2(b[2], b[3]);
  *(u32x4*)&out[i] = o;
}

__global__ __launch_bounds__(256) void cast2_f32_bf16(const float* __restrict__ i0,
                                                      const float* __restrict__ i1,
                                                      u16* __restrict__ o0,
                                                      u16* __restrict__ o1) {
  const float* in = blockIdx.y ? i1 : i0;
  u16* out = blockIdx.y ? o1 : o0;
  size_t i = ((size_t)blockIdx.x * 256 + threadIdx.x) * 8;
  f32x4 a = *(const f32x4*)&in[i];
  f32x4 b = *(const f32x4*)&in[i + 4];
  u32x4 o;
  o[0] = pk2(a[0], a[1]);
  o[1] = pk2(a[2], a[3]);
  o[2] = pk2(b[0], b[1]);
  o[3] = pk2(b[2], b[3]);
  *(u32x4*)&out[i] = o;
}

// ---------------- transpose+cast: in [K,N] fp32 -> out [N,K] bf16 ----------------
__global__ __launch_bounds__(256) void transpose2_f32_bf16(const float* __restrict__ i0,
                                                           const float* __restrict__ i1,
                                                           u16* __restrict__ o0,
                                                           u16* __restrict__ o1,
                                                           int K, int N) {
  const float* in = blockIdx.z ? i1 : i0;
  u16* out = blockIdx.z ? o1 : o0;
  __shared__ u16 tile[64][72];
  int k0 = blockIdx.y * 64, n0 = blockIdx.x * 64;
  int t = threadIdx.x;
#pragma unroll
  for (int i = 0; i < 4; ++i) {
    int idx = i * 256 + t;
    int r = idx >> 4;
    int c4 = (idx & 15) << 2;
    f32x4 v = *(const f32x4*)&in[(size_t)(k0 + r) * N + n0 + c4];
#pragma unroll
    for (int j = 0; j < 4; ++j) tile[r][c4 + j] = f2bf(v[j]);
  }
  __syncthreads();
#pragma unroll
  for (int i = 0; i < 4; ++i) {
    int idx = i * 256 + t;
    int r = idx >> 4;
    int c4 = (idx & 15) << 2;
    u16x4 v;
    v[0] = tile[c4 + 0][r];
    v[1] = tile[c4 + 1][r];
    v[2] = tile[c4 + 2][r];
    v[3] = tile[c4 + 3][r];
    *(u16x4*)&out[(size_t)(n0 + r) * K + k0 + c4] = v;
  }
}

__global__ __launch_bounds__(256) void transpose_f32_bf16(const float* __restrict__ in,
                                                          u16* __restrict__ out,
                                                          int K, int N) {
  __shared__ u16 tile[64][72];
  int k0 = blockIdx.y * 64, n0 = blockIdx.x * 64;
  int t = threadIdx.x;
#pragma unroll
  for (int i = 0; i < 4; ++i) {
    int idx = i * 256 + t;
    int r = idx >> 4;
    int c4 = (idx & 15) << 2;
    f32x4 v = *(const f32x4*)&in[(size_t)(k0 + r) * N + n0 + c4];
#pragma unroll
    for (int j = 0; j < 4; ++j) tile[r][c4 + j] = f2bf(v[j]);
  }
  __syncthreads();
#pragma unroll
  for (int i = 0; i < 4; ++i) {
    int idx = i * 256 + t;
    int r = idx >> 4;
    int c4 = (idx & 15) << 2;
    u16x4 v;
    v[0] = tile[c4 + 0][r];
    v[1] = tile[c4 + 1][r];
    v[2] = tile[c4 + 2][r];
    v[3] = tile[c4 + 3][r];
    *(u16x4*)&out[(size_t)(n0 + r) * K + k0 + c4] = v;
  }
}

// ------------- absorb_q: Wq2T[h*64+ld][k] = sum_dk Wkr[ld][dk] * Wq[k][h*128+dk] -------------
__global__ __launch_bounds__(256) void absorb_q(const u16* __restrict__ Wkr,
                                                const u16* __restrict__ Wqb,
                                                u16* __restrict__ Wq2T) {
  int kb = blockIdx.x, h = blockIdx.y;
  int t = threadIdx.x, w = t >> 6, lane = t & 63, lq = lane & 15, hi = lane >> 4;
  int k0 = kb * 128 + w * 32;
  f32x4 acc[4][2];
#pragma unroll
  for (int i = 0; i < 4; ++i)
#pragma unroll
    for (int j = 0; j < 2; ++j) acc[i][j] = (f32x4){0.f, 0.f, 0.f, 0.f};
#pragma unroll
  for (int kk = 0; kk < 4; ++kk) {
    bf16x8 a[4], bb[2];
#pragma unroll
    for (int fld = 0; fld < 4; ++fld)
      a[fld] = *(const bf16x8*)&Wkr[(fld * 16 + lq) * 128 + kk * 32 + hi * 8];
#pragma unroll
    for (int fk = 0; fk < 2; ++fk)
      bb[fk] = *(const bf16x8*)&Wqb[(size_t)(k0 + fk * 16 + lq) * 2048 + h * 128 + kk * 32 + hi * 8];
#pragma unroll
    for (int fld = 0; fld < 4; ++fld)
#pragma unroll
      for (int fk = 0; fk < 2; ++fk)
        acc[fld][fk] = __builtin_amdgcn_mfma_f32_16x16x32_bf16(a[fld], bb[fk], acc[fld][fk], 0, 0, 0);
  }
#pragma unroll
  for (int fld = 0; fld < 4; ++fld)
#pragma unroll
    for (int fk = 0; fk < 2; ++fk)
#pragma unroll
      for (int r = 0; r < 4; ++r)
        Wq2T[(size_t)(h * 64 + fld * 16 + hi * 4 + r) * 2048 + k0 + fk * 16 + lq] =
            f2bf(acc[fld][fk][r]);
}

// ------------- absorb_o: W2T[n][h*64+ld] = sum_dv WoutT[n][h*128+dv] * Wvr[ld][dv] -------------
__global__ __launch_bounds__(256) void absorb_o(const u16* __restrict__ WoutT,
                                                const u16* __restrict__ Wvr,
                                                u16* __restrict__ W2T) {
  int nb = blockIdx.x, h = blockIdx.y;
  int t = threadIdx.x, w = t >> 6, lane = t & 63, lq = lane & 15, hi = lane >> 4;
  int n0 = nb * 128 + w * 32;
  f32x4 acc[2][4];
#pragma unroll
  for (int i = 0; i < 2; ++i)
#pragma unroll
    for (int j = 0; j < 4; ++j) acc[i][j] = (f32x4){0.f, 0.f, 0.f, 0.f};
#pragma unroll
  for (int kk = 0; kk < 4; ++kk) {
    bf16x8 a[2], bb[4];
#pragma unroll
    for (int fn = 0; fn < 2; ++fn)
      a[fn] = *(const bf16x8*)&WoutT[(size_t)(n0 + fn * 16 + lq) * 2048 + h * 128 + kk * 32 + hi * 8];
#pragma unroll
    for (int fld = 0; fld < 4; ++fld)
      bb[fld] = *(const bf16x8*)&Wvr[(fld * 16 + lq) * 128 + kk * 32 + hi * 8];
#pragma unroll
    for (int fn = 0; fn < 2; ++fn)
#pragma unroll
      for (int fld = 0; fld < 4; ++fld)
        acc[fn][fld] = __builtin_amdgcn_mfma_f32_16x16x32_bf16(a[fn], bb[fld], acc[fn][fld], 0, 0, 0);
  }
#pragma unroll
  for (int fn = 0; fn < 2; ++fn)
#pragma unroll
    for (int fld = 0; fld < 4; ++fld)
#pragma unroll
      for (int r = 0; r < 4; ++r)
        W2T[(size_t)(n0 + fn * 16 + hi * 4 + r) * 1024 + h * 64 + fld * 16 + lq] =
            f2bf(acc[fn][fld][r]);
}

// ------------- absorb_bq (fp32) -------------
__global__ __launch_bounds__(256) void absorb_bq(const float* __restrict__ bq,
                                                 const float* __restrict__ Wkr,
                                                 float* __restrict__ bq2) {
  int n = blockIdx.x * 256 + threadIdx.x;
  int h = n >> 6, ld = n & 63;
  float s = 0.f;
#pragma unroll 8
  for (int dk = 0; dk < 128; ++dk) s += bq[h * 128 + dk] * Wkr[ld * 128 + dk];
  bq2[n] = s;
}

// ------------- deep-pipelined GEMM: 256x256 tile, BK=32, 4 LDS sub-buffers, counted vmcnt -------------
// C[M,N] = A[M,K] @ W + bias with Wt[N,K] (bf16).  512 threads, 8 waves (2M x 4N).
template <bool OF32>
__global__ __launch_bounds__(512, 2) void gemm8p(const u16* __restrict__ A0,
                                                 const u16* __restrict__ A1,
                                                 const u16* __restrict__ A2,
                                                 const u16* __restrict__ W0,
                                                 const u16* __restrict__ W1,
                                                 const u16* __restrict__ W2,
                                                 const float* __restrict__ b0,
                                                 const float* __restrict__ b1,
                                                 const float* __restrict__ b2,
                                                 void* __restrict__ C0,
                                                 void* __restrict__ C1,
                                                 void* __restrict__ C2,
                                                 int N, int K) {
  __shared__ u16 lds[4][2][256 * 32];  // [buf][A/B][row*32 + col], rows 64B, slot-XOR swizzled
  int z = blockIdx.z;
  const u16* A = z == 0 ? A0 : (z == 1 ? A1 : A2);
  const u16* Wt = z == 0 ? W0 : (z == 1 ? W1 : W2);
  const float* bias = z == 0 ? b0 : (z == 1 ? b1 : b2);
  void* Cv = z == 0 ? C0 : (z == 1 ? C1 : C2);

  int m0 = blockIdx.y * 256, n0 = blockIdx.x * 256;
  int t = threadIdx.x;
  int lane = t & 63, lq = lane & 15, hi = lane >> 4;
  int w = t >> 6, wm = w >> 2, wn = w & 3;
  int NT = K >> 5;

  auto stage = [&](int q, int kt) {
    u16* lA = &lds[q][0][0];
    u16* lB = &lds[q][1][0];
    int kb = kt * 32;
#pragma unroll
    for (int i = 0; i < 2; ++i) {
      int idx = i * 512 + t;
      int row = idx >> 2, c = idx & 3;
      glds16(&A[(size_t)(m0 + row) * K + kb + ((c ^ (row & 3)) << 3)], lA + idx * 8);
    }
#pragma unroll
    for (int i = 0; i < 2; ++i) {
      int idx = i * 512 + t;
      int row = idx >> 2, c = idx & 3;
      glds16(&Wt[(size_t)(n0 + row) * K + kb + ((c ^ (row & 3)) << 3)], lB + idx * 8);
    }
  };

  f32x4 acc[8][4];
#pragma unroll
  for (int im = 0; im < 8; ++im)
#pragma unroll
    for (int fn = 0; fn < 4; ++fn) acc[im][fn] = (f32x4){0.f, 0.f, 0.f, 0.f};

  stage(0, 0);
  stage(1, 1);
  asm volatile("s_waitcnt vmcnt(4)" ::: "memory");  // tile 0 landed
  __builtin_amdgcn_s_barrier();

  for (int tt = 0; tt < NT; ++tt) {
    int q = tt & 3;
    if (tt + 2 < NT) stage((tt + 2) & 3, tt + 2);
    const u16* lA = &lds[q][0][0];
    const u16* lB = &lds[q][1][0];
    bf16x8 bf[4];
#pragma unroll
    for (int fn = 0; fn < 4; ++fn) {
      int row = wn * 64 + fn * 16 + lq;
      bf[fn] = *(const bf16x8*)&lB[row * 32 + ((hi ^ (row & 3)) << 3)];
    }
    __builtin_amdgcn_s_setprio(1);
#pragma unroll
    for (int im = 0; im < 8; ++im) {
      int row = wm * 128 + im * 16 + lq;
      bf16x8 af = *(const bf16x8*)&lA[row * 32 + ((hi ^ (row & 3)) << 3)];
#pragma unroll
      for (int fn = 0; fn < 4; ++fn)
        acc[im][fn] = __builtin_amdgcn_mfma_f32_16x16x32_bf16(af, bf[fn], acc[im][fn], 0, 0, 0);
    }
    __builtin_amdgcn_s_setprio(0);
    // stage(tt+1) must be complete before next iteration reads it:
    if (tt + 2 < NT)
      asm volatile("s_waitcnt vmcnt(4)" ::: "memory");   // allow stage(tt+2) in flight
    else
      asm volatile("s_waitcnt vmcnt(0)" ::: "memory");   // tail drain
    __builtin_amdgcn_s_barrier();
  }

  // epilogue
#pragma unroll
  for (int im = 0; im < 8; ++im)
#pragma unroll
    for (int fn = 0; fn < 4; ++fn) {
      int col = n0 + wn * 64 + fn * 16 + lq;
      float bv = bias[col];
      int rbase = m0 + wm * 128 + im * 16 + hi * 4;
#pragma unroll
      for (int r = 0; r < 4; ++r) {
        float v = acc[im][fn][r] + bv;
        if constexpr (OF32)
          ((float*)Cv)[(size_t)(rbase + r) * N + col] = v;
        else
          ((u16*)Cv)[(size_t)(rbase + r) * N + col] = f2bf(v);
      }
    }
}

// ------------- transpose_lv: LV[b][s][h*64+ld] -> LVt[bh][ld][s], sigma-permuted per 32-s -------------
__global__ __launch_bounds__(256) void transpose_lv(const u16* __restrict__ LV,
                                                    u16* __restrict__ out) {
  __shared__ u16 tile[64 * 72];
  int st = blockIdx.x, bh = blockIdx.y;
  int b = bh >> 4, h = bh & 15;
  int t = threadIdx.x;
  int s0 = st * 64;
#pragma unroll
  for (int i = 0; i < 2; ++i) {
    int idx = i * 256 + t;
    int sr = idx >> 3, c8 = idx & 7;
    bf16x8 v = *(const bf16x8*)&LV[(size_t)(b * S_LEN + s0 + sr) * 1024 + h * 64 + c8 * 8];
    int pos = (sr & 32) + ((sr & 12) << 1) + ((sr & 16) >> 2) + (sr & 3);
#pragma unroll
    for (int j = 0; j < 8; ++j) tile[(c8 * 8 + j) * 72 + pos] = (u16)v[j];
  }
  __syncthreads();
  u16* ob = out + (size_t)bh * 64 * S_LEN;
#pragma unroll
  for (int i = 0; i < 2; ++i) {
    int idx = i * 256 + t;
    int ld = idx >> 3, c8 = idx & 7;
    bf16x8 v = *(const bf16x8*)&tile[ld * 72 + c8 * 8];
    *(bf16x8*)&ob[(size_t)ld * S_LEN + s0 + c8 * 8] = v;
  }
}

// ------------- latent flash attention: QBLK=64, 1024 blocks (4/CU), 32KB LDS -------------
__global__ __launch_bounds__(256) void mla_attn5(const u16* __restrict__ Qp,
                                                 const u16* __restrict__ LK,
                                                 const u16* __restrict__ LVt,
                                                 u16* __restrict__ O) {
  __shared__ u16 smem[16384];
  int Lb = blockIdx.x + blockIdx.y * 8;
  int half = Lb >> 9;
  int i0 = Lb & 511;
  int xcd = i0 & 7, ii = i0 >> 3;
  int bh = xcd * 4 + (ii & 3);
  int pr = ii >> 2;
  int qsup = half ? (31 - pr) : pr;
  int b = bh >> 4, h = bh & 15;
  int t = threadIdx.x, w = t >> 6, lane = t & 63, lq = lane & 15, hi = lane >> 4;
  int lq7 = lq & 7;

  const u16* Kb = LK + (size_t)b * S_LEN * 1024 + h * 64;
  const u16* Vb = LVt + (size_t)bh * 64 * S_LEN;
  const float scale = 0.08838834764831845f;

  auto stage = [&](int buf, int k0) {
    u16* lK = smem + buf * 4096;
    u16* lV = smem + 8192 + buf * 4096;
#pragma unroll
    for (int i = 0; i < 2; ++i) {
      int idx = i * 256 + t;
      int row = idx >> 3, c8 = idx & 7;
      glds16(Kb + (size_t)(k0 + row) * 1024 + ((c8 ^ (row & 7)) << 3), lK + idx * 8);
    }
#pragma unroll
    for (int i = 0; i < 2; ++i) {
      int idx = i * 256 + t;
      int row = idx >> 3, c8 = idx & 7;
      glds16(Vb + (size_t)row * S_LEN + k0 + ((c8 ^ (row & 7)) << 3), lV + idx * 8);
    }
  };

  int qb = qsup * 64;
  int nt = qsup + 1;
  int q0 = qb + w * 16;
  int kmax = q0 + 16;

  bf16x8 qf[2];
  {
    const u16* Qrow = Qp + (size_t)(b * S_LEN + q0 + lq) * 1024 + h * 64;
    qf[0] = *(const bf16x8*)&Qrow[hi * 8];
    qf[1] = *(const bf16x8*)&Qrow[32 + hi * 8];
  }

  f32x4 acc[4];
#pragma unroll
  for (int f = 0; f < 4; ++f) acc[f] = (f32x4){0.f, 0.f, 0.f, 0.f};
  float m = -1e30f, l = 0.f;

  stage(0, 0);
  __syncthreads();
  for (int tt = 0; tt < nt; ++tt) {
    int cur = tt & 1;
    if (tt + 1 < nt) stage(cur ^ 1, (tt + 1) * 64);
    int k0 = tt * 64;
    if (k0 < kmax) {
      const u16* lK = smem + cur * 4096;
      const u16* lV = smem + 8192 + cur * 4096;
      f32x4 sc[4];
#pragma unroll
      for (int kf = 0; kf < 4; ++kf) sc[kf] = (f32x4){0.f, 0.f, 0.f, 0.f};
      __builtin_amdgcn_s_setprio(1);
#pragma unroll
      for (int kf = 0; kf < 4; ++kf) {
        const u16* kr = lK + (kf * 16 + lq) * 64;
#pragma unroll
        for (int d0 = 0; d0 < 2; ++d0) {
          bf16x8 af = *(const bf16x8*)&kr[(((d0 << 2) + hi) ^ lq7) << 3];
          sc[kf] = __builtin_amdgcn_mfma_f32_16x16x32_bf16(af, qf[d0], sc[kf], 0, 0, 0);
        }
      }
      __builtin_amdgcn_s_setprio(0);
      int q = q0 + lq;
      float sv[16];
#pragma unroll
      for (int kf = 0; kf < 4; ++kf)
#pragma unroll
        for (int r = 0; r < 4; ++r) sv[kf * 4 + r] = sc[kf][r] * scale;
      if (k0 + 63 > q0) {
#pragma unroll
        for (int kf = 0; kf < 4; ++kf)
#pragma unroll
          for (int r = 0; r < 4; ++r)
            if (k0 + kf * 16 + hi * 4 + r > q) sv[kf * 4 + r] = -1e30f;
      }
      float tm = sv[0];
#pragma unroll
      for (int j = 1; j < 16; ++j) tm = fmaxf(tm, sv[j]);
      tm = fmaxf(tm, __shfl_xor(tm, 16));
      tm = fmaxf(tm, __shfl_xor(tm, 32));
      float p[16], ps = 0.f;
      if (__all(tm <= m + 8.f)) {
#pragma unroll
        for (int j = 0; j < 16; ++j) { p[j] = __expf(sv[j] - m); ps += p[j]; }
        ps += __shfl_xor(ps, 16);
        ps += __shfl_xor(ps, 32);
        l += ps;
      } else {
        float mnew = fmaxf(m, tm);
        float alpha = __expf(m - mnew);
#pragma unroll
        for (int j = 0; j < 16; ++j) { p[j] = __expf(sv[j] - mnew); ps += p[j]; }
        ps += __shfl_xor(ps, 16);
        ps += __shfl_xor(ps, 32);
        l = l * alpha + ps;
        m = mnew;
#pragma unroll
        for (int f = 0; f < 4; ++f) {
          acc[f][0] *= alpha; acc[f][1] *= alpha;
          acc[f][2] *= alpha; acc[f][3] *= alpha;
        }
      }
      bf16x8 pb[2];
#pragma unroll
      for (int ks = 0; ks < 2; ++ks) {
        union { u32x4 u; bf16x8 v; } pu;
#pragma unroll
        for (int wd = 0; wd < 4; ++wd) pu.u[wd] = pk2(p[ks * 8 + 2 * wd], p[ks * 8 + 2 * wd + 1]);
        pb[ks] = pu.v;
      }
      __builtin_amdgcn_s_setprio(1);
#pragma unroll
      for (int f = 0; f < 4; ++f) {
        const u16* vr = lV + (f * 16 + lq) * 64;
#pragma unroll
        for (int ks = 0; ks < 2; ++ks) {
          bf16x8 va = *(const bf16x8*)&vr[(((ks << 2) + hi) ^ lq7) << 3];
          acc[f] = __builtin_amdgcn_mfma_f32_16x16x32_bf16(va, pb[ks], acc[f], 0, 0, 0);
        }
      }
      __builtin_amdgcn_s_setprio(0);
    }
    __syncthreads();
  }
  {
    float inv = 1.f / l;
    int qloc = w * 16 + lq;
#pragma unroll
    for (int f = 0; f < 4; ++f)
#pragma unroll
      for (int r = 0; r < 4; ++r) {
        int col = f * 16 + hi * 4 + r;
        smem[qloc * 64 + (((col >> 3) ^ lq7) << 3) + (col & 7)] = f2bf(acc[f][r] * inv);
      }
  }
  __syncthreads();
#pragma unroll
  for (int i = 0; i < 2; ++i) {
    int cid = i * 256 + t;
    int q = cid >> 3, ch = cid & 7;
    bf16x8 v = *(const bf16x8*)&smem[q * 64 + ((ch ^ (q & 7)) << 3)];
    *(bf16x8*)&O[(size_t)(b * S_LEN + qb + q) * 1024 + h * 64 + (ch << 3)] = v;
  }
}

extern "C" void kernel_launch(void* const* d_in, const int* in_sizes, int n_in,
                              void* d_out, int out_size, void* d_ws, size_t ws_size,
                              hipStream_t stream) {
  const float* queries = (const float*)d_in[0];
  const float* keys    = (const float*)d_in[1];
  const float* values  = (const float*)d_in[2];
  const float* Wq      = (const float*)d_in[3];
  const float* bq      = (const float*)d_in[4];
  const float* Wlk     = (const float*)d_in[5];
  const float* blk     = (const float*)d_in[6];
  const float* Wlv     = (const float*)d_in[7];
  const float* blv     = (const float*)d_in[8];
  const float* Wkr     = (const float*)d_in[9];
  const float* Wvr     = (const float*)d_in[10];
  const float* Wout    = (const float*)d_in[11];
  const float* bout    = (const float*)d_in[12];

  u16* ws = (u16*)d_ws;
  u16* WqBf  = ws; ws += (size_t)2048 * 2048;
  u16* WkrBf = ws; ws += 64 * 128;
  u16* WvrBf = ws; ws += 64 * 128;
  u16* WoutT = ws; ws += (size_t)2048 * 2048;
  u16* WlkT  = ws; ws += (size_t)1024 * 2048;
  u16* WlvT  = ws; ws += (size_t)1024 * 2048;
  u16* Wq2T  = ws; ws += (size_t)1024 * 2048;
  u16* W2T   = ws; ws += (size_t)2048 * 1024;
  float* bq2 = (float*)ws; ws += 2048;
  u16* Qin   = ws; ws += (size_t)4096 * 2048;
  u16* Kin   = ws; ws += (size_t)4096 * 2048;
  u16* Vin   = ws; ws += (size_t)4096 * 2048;
  u16* Qp    = ws; ws += (size_t)4096 * 1024;
  u16* LKb   = ws; ws += (size_t)4096 * 1024;
  u16* LVb   = ws; ws += (size_t)4096 * 1024;
  u16* LVt = Kin;  // alias: written after projections consumed Kin
  u16* Ob  = Qin;  // alias: written after projections consumed Qin

  dim3 blk256(256);
  cast3_f32_bf16<<<dim3(4096, 3), blk256, 0, stream>>>(queries, keys, values, Qin, Kin, Vin);
  cast_f32_bf16<<<dim3(2048), blk256, 0, stream>>>(Wq, WqBf);
  cast2_f32_bf16<<<dim3(4, 2), blk256, 0, stream>>>(Wkr, Wvr, WkrBf, WvrBf);

  transpose2_f32_bf16<<<dim3(16, 32, 2), blk256, 0, stream>>>(Wlk, Wlv, WlkT, WlvT, 2048, 1024);
  transpose_f32_bf16<<<dim3(32, 32), blk256, 0, stream>>>(Wout, WoutT, 2048, 2048);

  absorb_q<<<dim3(16, 16), blk256, 0, stream>>>(WkrBf, WqBf, Wq2T);
  absorb_o<<<dim3(16, 16), blk256, 0, stream>>>(WoutT, WvrBf, W2T);
  absorb_bq<<<dim3(4), blk256, 0, stream>>>(bq, Wkr, bq2);

  gemm8p<false><<<dim3(4, 16, 3), dim3(512), 0, stream>>>(
      Qin, Kin, Vin, Wq2T, WlkT, WlvT, bq2, blk, blv, Qp, LKb, LVb, 1024, 2048);

  transpose_lv<<<dim3(32, 32), blk256, 0, stream>>>(LVb, LVt);

  mla_attn5<<<dim3(8, 128), blk256, 0, stream>>>(Qp, LKb, LVt, Ob);

  gemm8p<true><<<dim3(8, 16, 1), dim3(512), 0, stream>>>(
      Ob, Ob, Ob, W2T, W2T, W2T, bout, bout, bout, d_out, d_out, d_out, 2048, 1024);
}